// Round 7
// baseline (928.569 us; speedup 1.0000x reference)
//
#include <hip/hip_runtime.h>
#include <hip/hip_bf16.h>

// ---------------------------------------------------------------------------
// GraphEncoder: SAGE(6->1024) -> LN -> ReLU -> SAGE(1024->1024) -> LN -> ReLU
//   -> concat(Fourier feats) -> per-graph mean pool -> FC(2048->256) -> LN
// gemm2: 256x256 8-phase counted-vmcnt schedule (m201 template, plain HIP)
// ---------------------------------------------------------------------------

#define N_NODES 50000
#define N_EDGES 500000
#define N_GRAPHS 64
#define IN_DIM 6
#define GNN_DIM 1024
#define OUT_DIM 256
#define CAT_DIM 2048
#define M_PAD 50176   // 196 * 256

typedef __attribute__((ext_vector_type(8))) short short8;
typedef __attribute__((ext_vector_type(4))) float f32x4;

// ---------------- static device scratch (allocated at module load) ---------
__device__ int g_cnt[N_NODES + 1];
__device__ int g_cursor[N_NODES];
__device__ int g_gcnt[N_GRAPHS];
__device__ int g_rowptr[N_NODES + 1];
__device__ int g_goff[N_GRAPHS + 1];
__device__ int g_esrc[N_EDGES];
__device__ __attribute__((aligned(256))) unsigned short g_w2lt[(size_t)GNN_DIM * GNN_DIM];
__device__ __attribute__((aligned(256))) unsigned short g_w2rt[(size_t)GNN_DIM * GNN_DIM];
__device__ float g_agg1[(size_t)N_NODES * IN_DIM];
__device__ __attribute__((aligned(256))) unsigned short g_h[(size_t)M_PAD * GNN_DIM];
__device__ __attribute__((aligned(256))) unsigned short g_agg2[(size_t)M_PAD * GNN_DIM];
__device__ __attribute__((aligned(256))) unsigned short g_h2[(size_t)M_PAD * GNN_DIM];
__device__ float g_gpool[(size_t)N_GRAPHS * CAT_DIM];

__device__ __forceinline__ float bflo(int u) { return __uint_as_float(((unsigned)u) << 16); }
__device__ __forceinline__ float bfhi(int u) { return __uint_as_float(((unsigned)u) & 0xffff0000u); }
__device__ __forceinline__ unsigned short f2bf(float f) {
    unsigned u = __float_as_uint(f);
    unsigned rounded = u + 0x7fff + ((u >> 16) & 1);   // RNE
    return (unsigned short)(rounded >> 16);
}
__device__ __forceinline__ int pack2(unsigned short a, unsigned short b) {
    return (int)((unsigned)a | ((unsigned)b << 16));
}

// ---------------------------------------------------------------------------
// zero + CSR build
// ---------------------------------------------------------------------------
__global__ void zero_kernel() {          // grid 512 -> 131072 threads
    int i = blockIdx.x * 256 + threadIdx.x;
    if (i <= N_NODES) g_cnt[i] = 0;
    if (i < N_NODES) g_cursor[i] = 0;
    if (i < N_GRAPHS) g_gcnt[i] = 0;
    if (i < N_GRAPHS * CAT_DIM) g_gpool[i] = 0.f;
}

__global__ void count_kernel(const int* __restrict__ dst, const int* __restrict__ batch) {
    int i = blockIdx.x * 256 + threadIdx.x;
    if (i < N_EDGES) atomicAdd(&g_cnt[dst[i]], 1);
    if (i < N_NODES) atomicAdd(&g_gcnt[batch[i]], 1);
}

// two-level scan (rowptr) + graph-offset prefix (goff) in one kernel
__global__ __launch_bounds__(1024) void scan_kernel() {
    const int CH = 49;           // 1024 * 49 = 50176 >= N_NODES+1
    int t = threadIdx.x;
    int base = t * CH;
    int s = 0;
    #pragma unroll
    for (int i = 0; i < CH; ++i) {
        int n = base + i;
        s += (n < N_NODES) ? g_cnt[n] : 0;
    }
    int lane = t & 63, w = t >> 6;
    int x = s;
    #pragma unroll
    for (int off = 1; off < 64; off <<= 1) {
        int y = __shfl_up(x, off);
        if (lane >= off) x += y;
    }
    __shared__ int wsum[16], woff[16];
    if (lane == 63) wsum[w] = x;
    __syncthreads();
    if (t == 0) { int a = 0; for (int i = 0; i < 16; ++i) { woff[i] = a; a += wsum[i]; } }
    __syncthreads();
    int excl = x - s + woff[w];      // exclusive prefix at chunk start
    #pragma unroll
    for (int i = 0; i < CH; ++i) {
        int n = base + i;
        if (n <= N_NODES) g_rowptr[n] = excl;
        if (n < N_NODES) excl += g_cnt[n];
    }
    // goff: 64-thread wave prefix over g_gcnt (independent of rowptr work)
    if (t < 64) {
        int v = g_gcnt[t];
        int xx = v;
        #pragma unroll
        for (int off = 1; off < 64; off <<= 1) {
            int y = __shfl_up(xx, off);
            if ((t & 63) >= off) xx += y;
        }
        g_goff[t + 1] = xx;
        if (t == 0) g_goff[0] = 0;
    }
}

__global__ void scatter_kernel(const int* __restrict__ src, const int* __restrict__ dst) {
    int e = blockIdx.x * 256 + threadIdx.x;
    if (e >= N_EDGES) return;
    int d = dst[e];
    int pos = atomicAdd(&g_cursor[d], 1);
    g_esrc[g_rowptr[d] + pos] = src[e];
}

// ---------------------------------------------------------------------------
// Weight transpose f32 [K][N] -> bf16 [N][K], both weights in one dispatch
// ---------------------------------------------------------------------------
__global__ void transpose_bf16(const float* __restrict__ WA, const float* __restrict__ WB,
                               unsigned short* __restrict__ TA, unsigned short* __restrict__ TB) {
    __shared__ float tile[32][33];
    int id = blockIdx.x & 1023;
    const float* W = (blockIdx.x >> 10) ? WB : WA;
    unsigned short* Wt = (blockIdx.x >> 10) ? TB : TA;
    int bx = id & 31, by = id >> 5;
    int tx = threadIdx.x & 31, ty = threadIdx.x >> 5;  // 32x8
    for (int i = 0; i < 32; i += 8)
        tile[ty + i][tx] = W[(size_t)(by * 32 + ty + i) * GNN_DIM + bx * 32 + tx];
    __syncthreads();
    for (int i = 0; i < 32; i += 8)
        Wt[(size_t)(bx * 32 + ty + i) * GNN_DIM + by * 32 + tx] = f2bf(tile[tx][ty + i]);
}

// ---------------------------------------------------------------------------
// Layer 1: mean-agg of x (6-dim), transform, LN, ReLU -> h (bf16)
// ---------------------------------------------------------------------------
__global__ void l1_agg_kernel(const float* __restrict__ x) {
    int id = blockIdx.x * 256 + threadIdx.x;
    int n = id >> 3, slot = id & 7;
    if (n >= N_NODES || slot >= IN_DIM) return;
    int beg = g_rowptr[n], end = g_rowptr[n + 1];
    float s = 0.f;
    for (int i = beg; i < end; ++i) s += x[(size_t)g_esrc[i] * IN_DIM + slot];
    g_agg1[n * IN_DIM + slot] = s / (float)max(end - beg, 1);
}

// 8 nodes per block; weights held in registers (dims t*4..t*4+3 per thread)
__global__ __launch_bounds__(256) void l1_transform_kernel(
        const float* __restrict__ x,
        const float* __restrict__ W1l, const float* __restrict__ b1,
        const float* __restrict__ W1r, const float* __restrict__ g1,
        const float* __restrict__ be1) {
    int t = threadIdx.x;
    int nb = blockIdx.x * 8;                 // 6250 blocks * 8 = 50000 exact
    float4 wl[6], wr[6];
    #pragma unroll
    for (int k = 0; k < 6; ++k) {
        wl[k] = *(const float4*)&W1l[k * GNN_DIM + t * 4];
        wr[k] = *(const float4*)&W1r[k * GNN_DIM + t * 4];
    }
    float4 bb = *(const float4*)&b1[t * 4];
    float4 gg = *(const float4*)&g1[t * 4];
    float4 be = *(const float4*)&be1[t * 4];
    __shared__ float sx[48], sa[48];
    if (t < 48) sx[t] = x[nb * 6 + t];
    else if (t < 96) sa[t - 48] = g_agg1[nb * 6 + (t - 48)];
    __syncthreads();
    __shared__ float s1[4], s2[4];
    for (int u = 0; u < 8; ++u) {
        int n = nb + u;
        float4 v = bb;
        #pragma unroll
        for (int k = 0; k < 6; ++k) {
            float a = sa[u * 6 + k], xx = sx[u * 6 + k];
            v.x += a * wl[k].x + xx * wr[k].x;
            v.y += a * wl[k].y + xx * wr[k].y;
            v.z += a * wl[k].z + xx * wr[k].z;
            v.w += a * wl[k].w + xx * wr[k].w;
        }
        float sum = v.x + v.y + v.z + v.w;
        float sq  = v.x*v.x + v.y*v.y + v.z*v.z + v.w*v.w;
        #pragma unroll
        for (int off = 32; off; off >>= 1) { sum += __shfl_xor(sum, off); sq += __shfl_xor(sq, off); }
        if ((t & 63) == 0) { s1[t >> 6] = sum; s2[t >> 6] = sq; }
        __syncthreads();
        sum = s1[0] + s1[1] + s1[2] + s1[3];
        sq  = s2[0] + s2[1] + s2[2] + s2[3];
        __syncthreads();
        float mu = sum * (1.f / GNN_DIM);
        float var = sq * (1.f / GNN_DIM) - mu * mu;
        float rstd = rsqrtf(var + 1e-5f);
        float y0 = fmaxf((v.x - mu) * rstd * gg.x + be.x, 0.f);
        float y1 = fmaxf((v.y - mu) * rstd * gg.y + be.y, 0.f);
        float y2 = fmaxf((v.z - mu) * rstd * gg.z + be.z, 0.f);
        float y3 = fmaxf((v.w - mu) * rstd * gg.w + be.w, 0.f);
        int2 pk;
        pk.x = pack2(f2bf(y0), f2bf(y1));
        pk.y = pack2(f2bf(y2), f2bf(y3));
        *(int2*)(g_h + (size_t)n * GNN_DIM + t * 4) = pk;
    }
}

// ---------------------------------------------------------------------------
// Layer 2 aggregation: agg2[n] = mean of h[src] rows.
// Full row per wave (2 int4/lane), masked 8-edge batches -> 16 independent
// 1KB requests in flight per wave.
// ---------------------------------------------------------------------------
__global__ __launch_bounds__(256) void l2_agg_kernel() {
    int w = threadIdx.x >> 6, lane = threadIdx.x & 63;
    int n = blockIdx.x * 4 + w;              // 12500 blocks * 4 = 50000 exact
    int beg = g_rowptr[n], end = g_rowptr[n + 1];
    float s[16];
    #pragma unroll
    for (int j = 0; j < 16; ++j) s[j] = 0.f;
    const int4* hp = (const int4*)g_h;       // row = 128 int4
    for (int i = beg; i < end; i += 8) {
        int idx[8]; float msk[8]; int4 va[8], vb[8];
        #pragma unroll
        for (int j = 0; j < 8; ++j) {
            int e = i + j;
            int cl = (e < end) ? e : beg;    // beg valid since loop entered
            idx[j] = g_esrc[cl];
            msk[j] = (e < end) ? 1.f : 0.f;
        }
        #pragma unroll
        for (int j = 0; j < 8; ++j) {
            va[j] = hp[(size_t)idx[j] * 128 + lane];
            vb[j] = hp[(size_t)idx[j] * 128 + 64 + lane];
        }
        #pragma unroll
        for (int j = 0; j < 8; ++j) {
            float m = msk[j];
            s[0]  += m * bflo(va[j].x); s[1]  += m * bfhi(va[j].x);
            s[2]  += m * bflo(va[j].y); s[3]  += m * bfhi(va[j].y);
            s[4]  += m * bflo(va[j].z); s[5]  += m * bfhi(va[j].z);
            s[6]  += m * bflo(va[j].w); s[7]  += m * bfhi(va[j].w);
            s[8]  += m * bflo(vb[j].x); s[9]  += m * bfhi(vb[j].x);
            s[10] += m * bflo(vb[j].y); s[11] += m * bfhi(vb[j].y);
            s[12] += m * bflo(vb[j].z); s[13] += m * bfhi(vb[j].z);
            s[14] += m * bflo(vb[j].w); s[15] += m * bfhi(vb[j].w);
        }
    }
    float inv = 1.f / (float)max(end - beg, 1);
    int4 o0, o1;
    o0.x = pack2(f2bf(s[0] * inv),  f2bf(s[1] * inv));
    o0.y = pack2(f2bf(s[2] * inv),  f2bf(s[3] * inv));
    o0.z = pack2(f2bf(s[4] * inv),  f2bf(s[5] * inv));
    o0.w = pack2(f2bf(s[6] * inv),  f2bf(s[7] * inv));
    o1.x = pack2(f2bf(s[8] * inv),  f2bf(s[9] * inv));
    o1.y = pack2(f2bf(s[10] * inv), f2bf(s[11] * inv));
    o1.z = pack2(f2bf(s[12] * inv), f2bf(s[13] * inv));
    o1.w = pack2(f2bf(s[14] * inv), f2bf(s[15] * inv));
    *(int4*)(g_agg2 + (size_t)n * GNN_DIM + (size_t)lane * 8) = o0;
    *(int4*)(g_agg2 + (size_t)n * GNN_DIM + 512 + (size_t)lane * 8) = o1;
}

// ---------------------------------------------------------------------------
// Layer 2 GEMM: h2 = agg2 @ W2_l + h @ W2_r + b2  (bf16 MFMA)
// 256x256 tile, BK=64, 512 thr (8 waves 2Mx4N), 8-phase counted-vmcnt
// schedule; XOR-swizzled LDS (linear dest + pre-swizzled source); XCD remap.
// 32 K-tiles: kt 0-15 = seg0 (agg2 x W2l^T), kt 16-31 = seg1 (h x W2r^T).
// ---------------------------------------------------------------------------
#define NKT 32

__device__ __forceinline__ int swz(int row, int krd) {
    return row * 64 + ((((krd) * 2) ^ ((row & 7) << 4)) >> 1);
}

__device__ __forceinline__ void stage_half(const unsigned short* __restrict__ src,
        int src_row0, int k0, unsigned short* lds_base, int tid) {
    #pragma unroll
    for (int u = 0; u < 2; ++u) {
        int c = u * 512 + tid;           // 0..1023
        int r = c >> 3;                  // 0..127 (row within half)
        int kb = (c & 7) * 16;           // byte col within row
        int kbs = kb ^ ((r & 7) << 4);   // inverse-swizzled source col
        __builtin_amdgcn_global_load_lds(
            (const __attribute__((address_space(1))) void*)(src + (size_t)(src_row0 + r) * GNN_DIM + k0 + (kbs >> 1)),
            (__attribute__((address_space(3))) void*)(lds_base + r * 64 + (c & 7) * 8), 16, 0, 0);
    }
}

__global__ __launch_bounds__(512, 2) void gemm2_kernel(const float* __restrict__ bias) {
    __shared__ __attribute__((aligned(16))) unsigned short As[2][256 * 64];
    __shared__ __attribute__((aligned(16))) unsigned short Bs[2][256 * 64];
    // XCD-bijective remap: 784 blocks = 8 XCDs x 98; bn fastest within XCD.
    int i = blockIdx.x;
    int g = (i & 7) * 98 + (i >> 3);     // 0..783
    int bm = g >> 2, bn = g & 3;
    int row0 = bm * 256, col0 = bn * 256;
    int tid = threadIdx.x;
    int lane = tid & 63, wid = tid >> 6;
    int wr = wid >> 2, wc = wid & 3;     // 2Mx4N waves; wave owns 128x64
    int l15 = lane & 15, l16 = lane >> 4;
    f32x4 acc[8][4] = {};

#define STG_A(kt) do { int sseg = (kt) >> 4, sk0 = ((kt) & 15) * 64;                     \
        const unsigned short* S_ = sseg ? g_h : g_agg2;                                  \
        stage_half(S_, row0,       sk0, &As[(kt) & 1][0],        tid);                   \
        stage_half(S_, row0 + 128, sk0, &As[(kt) & 1][128 * 64], tid); } while (0)
#define STG_B(kt, hh) do { int sseg = (kt) >> 4, sk0 = ((kt) & 15) * 64;                 \
        const unsigned short* S_ = sseg ? g_w2rt : g_w2lt;                               \
        stage_half(S_, col0 + (hh) * 128, sk0, &Bs[(kt) & 1][(hh) * 128 * 64], tid); } while (0)

#define PHASE(bi, p, STAGES, VMW) do {                                                   \
    short8 a00, a01, a10, a11;                                                           \
    if ((p) == 0) {                                                                      \
        _Pragma("unroll")                                                                \
        for (int nf = 0; nf < 4; ++nf) {                                                 \
            int brow = wc * 64 + nf * 16 + l15;                                          \
            bfr[nf][0] = *(const short8*)&Bs[bi][swz(brow, l16 * 8)];                    \
            bfr[nf][1] = *(const short8*)&Bs[bi][swz(brow, 32 + l16 * 8)];               \
        }                                                                                \
    }                                                                                    \
    { int ar0 = wr * 128 + (2 * (p) + 0) * 16 + l15;                                     \
      int ar1 = wr * 128 + (2 * (p) + 1) * 16 + l15;                                     \
      a00 = *(const short8*)&As[bi][swz(ar0, l16 * 8)];                                  \
      a01 = *(const short8*)&As[bi][swz(ar0, 32 + l16 * 8)];                             \
      a10 = *(const short8*)&As[bi][swz(ar1, l16 * 8)];                                  \
      a11 = *(const short8*)&As[bi][swz(ar1, 32 + l16 * 8)]; }                           \
    STAGES;                                                                              \
    asm volatile("s_barrier" ::: "memory");                                              \
    asm volatile("s_waitcnt lgkmcnt(0)" ::: "memory");                                   \
    __builtin_amdgcn_s_setprio(1);                                                       \
    _Pragma("unroll")                                                                    \
    for (int nf = 0; nf < 4; ++nf) {                                                     \
        acc[2*(p)+0][nf] = __builtin_amdgcn_mfma_f32_16x16x32_bf16(a00, bfr[nf][0], acc[2*(p)+0][nf], 0, 0, 0); \
        acc[2*(p)+0][nf] = __builtin_amdgcn_mfma_f32_16x16x32_bf16(a01, bfr[nf][1], acc[2*(p)+0][nf], 0, 0, 0); \
        acc[2*(p)+1][nf] = __builtin_amdgcn_mfma_f32_16x16x32_bf16(a10, bfr[nf][0], acc[2*(p)+1][nf], 0, 0, 0); \
        acc[2*(p)+1][nf] = __builtin_amdgcn_mfma_f32_16x16x32_bf16(a11, bfr[nf][1], acc[2*(p)+1][nf], 0, 0, 0); \
    }                                                                                    \
    __builtin_amdgcn_s_setprio(0);                                                       \
    VMW;                                                                                 \
    asm volatile("s_barrier" ::: "memory");                                              \
} while (0)

    // Prologue: stage A(0),B(0) [buf0] + B(1) [buf1]; keep B(1) in flight.
    STG_A(0); STG_B(0, 0); STG_B(0, 1);
    STG_B(1, 0); STG_B(1, 1);
    asm volatile("s_waitcnt vmcnt(4)" ::: "memory");
    asm volatile("s_barrier" ::: "memory");

    #pragma unroll 1
    for (int it = 0; it < NKT / 2; ++it) {
        int t0 = 2 * it, t1 = 2 * it + 1;
        bool more0 = (t0 + 2 < NKT), more1 = (t1 + 2 < NKT);
        bool last = (it == NKT / 2 - 1);
        {   // K-tile t0 (buf0): phases 1-4
            short8 bfr[4][2];
            PHASE(0, 0, STG_A(t1), );
            PHASE(0, 1, if (more0) STG_B(t0 + 2, 0), );
            PHASE(0, 2, if (more0) STG_B(t0 + 2, 1), );
            PHASE(0, 3, ,
                  if (last) { asm volatile("s_waitcnt vmcnt(0)" ::: "memory"); }
                  else      { asm volatile("s_waitcnt vmcnt(4)" ::: "memory"); });
        }
        {   // K-tile t1 (buf1): phases 5-8
            short8 bfr[4][2];
            PHASE(1, 0, if (more0) STG_A(t0 + 2), );
            PHASE(1, 1, if (more1) STG_B(t1 + 2, 0), );
            PHASE(1, 2, if (more1) STG_B(t1 + 2, 1), );
            PHASE(1, 3, ,
                  if (last) { asm volatile("s_waitcnt vmcnt(0)" ::: "memory"); }
                  else      { asm volatile("s_waitcnt vmcnt(4)" ::: "memory"); });
        }
    }

    // Epilogue: bias + bf16 store
    #pragma unroll
    for (int mf = 0; mf < 8; ++mf) {
        #pragma unroll
        for (int nf = 0; nf < 4; ++nf) {
            int col = col0 + wc * 64 + nf * 16 + l15;
            int rb = row0 + wr * 128 + mf * 16 + l16 * 4;
            float bv = bias[col];
            #pragma unroll
            for (int r = 0; r < 4; ++r)
                g_h2[(size_t)(rb + r) * GNN_DIM + col] = f2bf(acc[mf][nf][r] + bv);
        }
    }
#undef PHASE
#undef STG_A
#undef STG_B
}

// ---------------------------------------------------------------------------
// Pool (h part): per node compute LN stats in-block (block sees full row),
// apply LN+ReLU, accumulate per graph. grid = 64 graphs * 8 node-slices.
// ---------------------------------------------------------------------------
__global__ __launch_bounds__(256) void pool_h_kernel(const float* __restrict__ g2,
                                                     const float* __restrict__ be2) {
    int g = blockIdx.x >> 3, sl = blockIdx.x & 7;
    int t = threadIdx.x;
    int beg = g_goff[g], end = g_goff[g + 1];
    int cnt = end - beg;
    int per = (cnt + 7) >> 3;
    int s0 = beg + sl * per, s1v = min(s0 + per, end);
    if (s0 >= s1v) return;                   // block-uniform
    float4 gg = *(const float4*)&g2[t * 4];
    float4 be = *(const float4*)&be2[t * 4];
    __shared__ float r1[4], r2[4];
    float a0 = 0.f, a1 = 0.f, a2 = 0.f, a3 = 0.f;
    int2 wv = *(const int2*)(g_h2 + (size_t)s0 * GNN_DIM + t * 4);
    for (int n = s0; n < s1v; ++n) {
        int2 w = wv;
        if (n + 1 < s1v) wv = *(const int2*)(g_h2 + (size_t)(n + 1) * GNN_DIM + t * 4);
        float v0 = bflo(w.x), v1 = bfhi(w.x), v2 = bflo(w.y), v3 = bfhi(w.y);
        float sum = v0 + v1 + v2 + v3;
        float sq  = v0*v0 + v1*v1 + v2*v2 + v3*v3;
        #pragma unroll
        for (int off = 32; off; off >>= 1) { sum += __shfl_xor(sum, off); sq += __shfl_xor(sq, off); }
        if ((t & 63) == 0) { r1[t >> 6] = sum; r2[t >> 6] = sq; }
        __syncthreads();
        sum = r1[0] + r1[1] + r1[2] + r1[3];
        sq  = r2[0] + r2[1] + r2[2] + r2[3];
        __syncthreads();
        float mu = sum * (1.f / GNN_DIM);
        float var = sq * (1.f / GNN_DIM) - mu * mu;
        float rstd = rsqrtf(var + 1e-5f);
        a0 += fmaxf((v0 - mu) * rstd * gg.x + be.x, 0.f);
        a1 += fmaxf((v1 - mu) * rstd * gg.y + be.y, 0.f);
        a2 += fmaxf((v2 - mu) * rstd * gg.z + be.z, 0.f);
        a3 += fmaxf((v3 - mu) * rstd * gg.w + be.w, 0.f);
    }
    atomicAdd(&g_gpool[g * CAT_DIM + t * 4 + 0], a0);
    atomicAdd(&g_gpool[g * CAT_DIM + t * 4 + 1], a1);
    atomicAdd(&g_gpool[g * CAT_DIM + t * 4 + 2], a2);
    atomicAdd(&g_gpool[g * CAT_DIM + t * 4 + 3], a3);
}

// ---------------------------------------------------------------------------
// Pool (fourier part): coords staged in LDS; thread handles 2 (scale,c)
// pairs, one proj shared by sin+cos. grid = 64 graphs * 2 node-slices.
// ---------------------------------------------------------------------------
__global__ __launch_bounds__(256) void pool_f_kernel(const float* __restrict__ coords,
                                                     const float* __restrict__ Bmat) {
    int g = blockIdx.x >> 1, sl = blockIdx.x & 1;
    int t = threadIdx.x;
    int beg = g_goff[g], end = g_goff[g + 1];
    int cnt = end - beg;
    int per = (cnt + 1) >> 1;
    int s0 = beg + sl * per, s1 = min(s0 + per, end);
    const float SC[4] = {1.f, 5.f, 10.f, 30.f};
    int si0 = t >> 7, c0 = t & 127;        // scales 0,1
    int si1 = si0 + 2;                     // scales 2,3
    float b00 = Bmat[c0] * SC[si0], b01 = Bmat[128 + c0] * SC[si0], b02 = Bmat[256 + c0] * SC[si0];
    float b10 = Bmat[c0] * SC[si1], b11 = Bmat[128 + c0] * SC[si1], b12 = Bmat[256 + c0] * SC[si1];
    float ss0 = 0.f, cs0 = 0.f, ss1 = 0.f, cs1 = 0.f;
    __shared__ float sc[256 * 3];
    for (int base = s0; base < s1; base += 256) {
        int m = min(256, s1 - base);
        __syncthreads();
        for (int q = t; q < 3 * m; q += 256) sc[q] = coords[base * 3 + q];
        __syncthreads();
        for (int i = 0; i < m; ++i) {
            float x0 = sc[i * 3], y0 = sc[i * 3 + 1], z0 = sc[i * 3 + 2];
            float p0 = x0 * b00 + y0 * b01 + z0 * b02;
            float p1 = x0 * b10 + y0 * b11 + z0 * b12;
            ss0 += __sinf(p0); cs0 += __cosf(p0);
            ss1 += __sinf(p1); cs1 += __cosf(p1);
        }
    }
    if (s0 < s1) {
        float* gp = g_gpool + g * CAT_DIM + GNN_DIM;
        atomicAdd(&gp[si0 * 256 + c0], ss0);
        atomicAdd(&gp[si0 * 256 + 128 + c0], cs0);
        atomicAdd(&gp[si1 * 256 + c0], ss1);
        atomicAdd(&gp[si1 * 256 + 128 + c0], cs1);
    }
}

// ---------------------------------------------------------------------------
// Final: out = LN(gpool/cnt @ Wfc + bfc)   (64 blocks x 256 threads)
// ---------------------------------------------------------------------------
__global__ __launch_bounds__(256) void final_kernel(
        const float* __restrict__ Wfc, const float* __restrict__ bfc,
        const float* __restrict__ gfc, const float* __restrict__ befc,
        float* __restrict__ out) {
    int g = blockIdx.x, t = threadIdx.x;
    int beg = g_goff[g], end = g_goff[g + 1];
    float inv = 1.f / (float)max(end - beg, 1);
    __shared__ float hg[CAT_DIM];
    for (int i = t; i < CAT_DIM; i += 256) hg[i] = g_gpool[g * CAT_DIM + i] * inv;
    __syncthreads();
    float acc = bfc[t];
    for (int k = 0; k < CAT_DIM; ++k) acc = fmaf(hg[k], Wfc[(size_t)k * OUT_DIM + t], acc);
    float sum = acc, sq = acc * acc;
    #pragma unroll
    for (int off = 32; off; off >>= 1) { sum += __shfl_xor(sum, off); sq += __shfl_xor(sq, off); }
    __shared__ float s1[4], s2[4];
    if ((t & 63) == 0) { s1[t >> 6] = sum; s2[t >> 6] = sq; }
    __syncthreads();
    sum = s1[0] + s1[1] + s1[2] + s1[3];
    sq  = s2[0] + s2[1] + s2[2] + s2[3];
    float mu = sum * (1.f / OUT_DIM);
    float var = sq * (1.f / OUT_DIM) - mu * mu;
    float rstd = rsqrtf(var + 1e-5f);
    out[g * OUT_DIM + t] = (acc - mu) * rstd * gfc[t] + befc[t];
}

// ---------------------------------------------------------------------------
extern "C" void kernel_launch(void* const* d_in, const int* in_sizes, int n_in,
                              void* d_out, int out_size, void* d_ws, size_t ws_size,
                              hipStream_t stream) {
    const float* x      = (const float*)d_in[0];
    const int*   ei     = (const int*)d_in[1];
    const float* coords = (const float*)d_in[2];
    const int*   batch  = (const int*)d_in[3];
    const float* Bmat   = (const float*)d_in[4];
    const float* W1l    = (const float*)d_in[5];
    const float* b1     = (const float*)d_in[6];
    const float* W1r    = (const float*)d_in[7];
    const float* g1     = (const float*)d_in[8];
    const float* be1    = (const float*)d_in[9];
    const float* W2l    = (const float*)d_in[10];
    const float* b2     = (const float*)d_in[11];
    const float* W2r    = (const float*)d_in[12];
    const float* g2     = (const float*)d_in[13];
    const float* be2    = (const float*)d_in[14];
    const float* Wfc    = (const float*)d_in[15];
    const float* bfc    = (const float*)d_in[16];
    const float* gfc    = (const float*)d_in[17];
    const float* befc   = (const float*)d_in[18];
    const int* src = ei;
    const int* dst = ei + N_EDGES;
    float* out = (float*)d_out;
    (void)in_sizes; (void)n_in; (void)out_size; (void)d_ws; (void)ws_size;

    unsigned short* w2lt;  hipGetSymbolAddress((void**)&w2lt, HIP_SYMBOL(g_w2lt));
    unsigned short* w2rt;  hipGetSymbolAddress((void**)&w2rt, HIP_SYMBOL(g_w2rt));

    zero_kernel<<<512, 256, 0, stream>>>();
    count_kernel<<<(N_EDGES + 255) / 256, 256, 0, stream>>>(dst, batch);
    scan_kernel<<<1, 1024, 0, stream>>>();
    scatter_kernel<<<(N_EDGES + 255) / 256, 256, 0, stream>>>(src, dst);

    transpose_bf16<<<2048, 256, 0, stream>>>(W2l, W2r, w2lt, w2rt);

    l1_agg_kernel<<<(N_NODES * 8 + 255) / 256, 256, 0, stream>>>(x);
    l1_transform_kernel<<<N_NODES / 8, 256, 0, stream>>>(x, W1l, b1, W1r, g1, be1);

    l2_agg_kernel<<<N_NODES / 4, 256, 0, stream>>>();

    gemm2_kernel<<<(M_PAD / 256) * (GNN_DIM / 256), 512, 0, stream>>>(b2);

    pool_h_kernel<<<N_GRAPHS * 8, 256, 0, stream>>>(g2, be2);
    pool_f_kernel<<<N_GRAPHS * 2, 256, 0, stream>>>(coords, Bmat);

    final_kernel<<<N_GRAPHS, 256, 0, stream>>>(Wfc, bfc, gfc, befc, out);
}

// Round 8
// 885.933 us; speedup vs baseline: 1.0481x; 1.0481x over previous
//
#include <hip/hip_runtime.h>
#include <hip/hip_bf16.h>

// ---------------------------------------------------------------------------
// GraphEncoder: SAGE(6->1024) -> LN -> ReLU -> SAGE(1024->1024) -> LN -> ReLU
//   -> concat(Fourier feats) -> per-graph mean pool -> FC(2048->256) -> LN
// gemm2: 128x128 m97-structure (measured 888 TF; 256^2 8-phase regressed due
// to 784-block/1-per-CU tail quantization -- see R7 post-mortem)
// ---------------------------------------------------------------------------

#define N_NODES 50000
#define N_EDGES 500000
#define N_GRAPHS 64
#define IN_DIM 6
#define GNN_DIM 1024
#define OUT_DIM 256
#define CAT_DIM 2048
#define M_PAD 50176   // 392 * 128  (392 = 8 XCDs * 49 row-groups)

typedef __attribute__((ext_vector_type(8))) short short8;
typedef __attribute__((ext_vector_type(4))) float f32x4;

// ---------------- static device scratch (allocated at module load) ---------
__device__ int g_cnt[N_NODES + 1];
__device__ int g_cursor[N_NODES];
__device__ int g_gcnt[N_GRAPHS];
__device__ int g_rowptr[N_NODES + 1];
__device__ int g_goff[N_GRAPHS + 1];
__device__ int g_esrc[N_EDGES];
__device__ __attribute__((aligned(256))) unsigned short g_w2lt[(size_t)GNN_DIM * GNN_DIM];
__device__ __attribute__((aligned(256))) unsigned short g_w2rt[(size_t)GNN_DIM * GNN_DIM];
__device__ float g_agg1[(size_t)N_NODES * IN_DIM];
__device__ __attribute__((aligned(256))) unsigned short g_h[(size_t)M_PAD * GNN_DIM];
__device__ __attribute__((aligned(256))) unsigned short g_agg2[(size_t)M_PAD * GNN_DIM];
__device__ __attribute__((aligned(256))) unsigned short g_h2[(size_t)M_PAD * GNN_DIM];
__device__ float g_gpool[(size_t)N_GRAPHS * CAT_DIM];

__device__ __forceinline__ float bflo(int u) { return __uint_as_float(((unsigned)u) << 16); }
__device__ __forceinline__ float bfhi(int u) { return __uint_as_float(((unsigned)u) & 0xffff0000u); }
__device__ __forceinline__ unsigned short f2bf(float f) {
    unsigned u = __float_as_uint(f);
    unsigned rounded = u + 0x7fff + ((u >> 16) & 1);   // RNE
    return (unsigned short)(rounded >> 16);
}
__device__ __forceinline__ int pack2(unsigned short a, unsigned short b) {
    return (int)((unsigned)a | ((unsigned)b << 16));
}

// ---------------------------------------------------------------------------
// zero + CSR build
// ---------------------------------------------------------------------------
__global__ void zero_kernel() {          // grid 512 -> 131072 threads
    int i = blockIdx.x * 256 + threadIdx.x;
    if (i <= N_NODES) g_cnt[i] = 0;
    if (i < N_NODES) g_cursor[i] = 0;
    if (i < N_GRAPHS) g_gcnt[i] = 0;
    if (i < N_GRAPHS * CAT_DIM) g_gpool[i] = 0.f;
}

__global__ void count_kernel(const int* __restrict__ dst, const int* __restrict__ batch) {
    int i = blockIdx.x * 256 + threadIdx.x;
    if (i < N_EDGES) atomicAdd(&g_cnt[dst[i]], 1);
    if (i < N_NODES) atomicAdd(&g_gcnt[batch[i]], 1);
}

// two-level scan (rowptr) + graph-offset prefix (goff) in one kernel
__global__ __launch_bounds__(1024) void scan_kernel() {
    const int CH = 49;           // 1024 * 49 = 50176 >= N_NODES+1
    int t = threadIdx.x;
    int base = t * CH;
    int s = 0;
    #pragma unroll
    for (int i = 0; i < CH; ++i) {
        int n = base + i;
        s += (n < N_NODES) ? g_cnt[n] : 0;
    }
    int lane = t & 63, w = t >> 6;
    int x = s;
    #pragma unroll
    for (int off = 1; off < 64; off <<= 1) {
        int y = __shfl_up(x, off);
        if (lane >= off) x += y;
    }
    __shared__ int wsum[16], woff[16];
    if (lane == 63) wsum[w] = x;
    __syncthreads();
    if (t == 0) { int a = 0; for (int i = 0; i < 16; ++i) { woff[i] = a; a += wsum[i]; } }
    __syncthreads();
    int excl = x - s + woff[w];      // exclusive prefix at chunk start
    #pragma unroll
    for (int i = 0; i < CH; ++i) {
        int n = base + i;
        if (n <= N_NODES) g_rowptr[n] = excl;
        if (n < N_NODES) excl += g_cnt[n];
    }
    // goff: 64-thread wave prefix over g_gcnt (independent of rowptr work)
    if (t < 64) {
        int v = g_gcnt[t];
        int xx = v;
        #pragma unroll
        for (int off = 1; off < 64; off <<= 1) {
            int y = __shfl_up(xx, off);
            if ((t & 63) >= off) xx += y;
        }
        g_goff[t + 1] = xx;
        if (t == 0) g_goff[0] = 0;
    }
}

__global__ void scatter_kernel(const int* __restrict__ src, const int* __restrict__ dst) {
    int e = blockIdx.x * 256 + threadIdx.x;
    if (e >= N_EDGES) return;
    int d = dst[e];
    int pos = atomicAdd(&g_cursor[d], 1);
    g_esrc[g_rowptr[d] + pos] = src[e];
}

// ---------------------------------------------------------------------------
// Weight transpose f32 [K][N] -> bf16 [N][K], both weights in one dispatch
// ---------------------------------------------------------------------------
__global__ void transpose_bf16(const float* __restrict__ WA, const float* __restrict__ WB,
                               unsigned short* __restrict__ TA, unsigned short* __restrict__ TB) {
    __shared__ float tile[32][33];
    int id = blockIdx.x & 1023;
    const float* W = (blockIdx.x >> 10) ? WB : WA;
    unsigned short* Wt = (blockIdx.x >> 10) ? TB : TA;
    int bx = id & 31, by = id >> 5;
    int tx = threadIdx.x & 31, ty = threadIdx.x >> 5;  // 32x8
    for (int i = 0; i < 32; i += 8)
        tile[ty + i][tx] = W[(size_t)(by * 32 + ty + i) * GNN_DIM + bx * 32 + tx];
    __syncthreads();
    for (int i = 0; i < 32; i += 8)
        Wt[(size_t)(bx * 32 + ty + i) * GNN_DIM + by * 32 + tx] = f2bf(tile[tx][ty + i]);
}

// ---------------------------------------------------------------------------
// Layer 1: mean-agg of x (6-dim), transform, LN, ReLU -> h (bf16)
// ---------------------------------------------------------------------------
__global__ void l1_agg_kernel(const float* __restrict__ x) {
    int id = blockIdx.x * 256 + threadIdx.x;
    int n = id >> 3, slot = id & 7;
    if (n >= N_NODES || slot >= IN_DIM) return;
    int beg = g_rowptr[n], end = g_rowptr[n + 1];
    float s = 0.f;
    for (int i = beg; i < end; ++i) s += x[(size_t)g_esrc[i] * IN_DIM + slot];
    g_agg1[n * IN_DIM + slot] = s / (float)max(end - beg, 1);
}

// 8 nodes per block; weights held in registers (dims t*4..t*4+3 per thread)
__global__ __launch_bounds__(256) void l1_transform_kernel(
        const float* __restrict__ x,
        const float* __restrict__ W1l, const float* __restrict__ b1,
        const float* __restrict__ W1r, const float* __restrict__ g1,
        const float* __restrict__ be1) {
    int t = threadIdx.x;
    int nb = blockIdx.x * 8;                 // 6250 blocks * 8 = 50000 exact
    float4 wl[6], wr[6];
    #pragma unroll
    for (int k = 0; k < 6; ++k) {
        wl[k] = *(const float4*)&W1l[k * GNN_DIM + t * 4];
        wr[k] = *(const float4*)&W1r[k * GNN_DIM + t * 4];
    }
    float4 bb = *(const float4*)&b1[t * 4];
    float4 gg = *(const float4*)&g1[t * 4];
    float4 be = *(const float4*)&be1[t * 4];
    __shared__ float sx[48], sa[48];
    if (t < 48) sx[t] = x[nb * 6 + t];
    else if (t < 96) sa[t - 48] = g_agg1[nb * 6 + (t - 48)];
    __syncthreads();
    __shared__ float s1[4], s2[4];
    for (int u = 0; u < 8; ++u) {
        int n = nb + u;
        float4 v = bb;
        #pragma unroll
        for (int k = 0; k < 6; ++k) {
            float a = sa[u * 6 + k], xx = sx[u * 6 + k];
            v.x += a * wl[k].x + xx * wr[k].x;
            v.y += a * wl[k].y + xx * wr[k].y;
            v.z += a * wl[k].z + xx * wr[k].z;
            v.w += a * wl[k].w + xx * wr[k].w;
        }
        float sum = v.x + v.y + v.z + v.w;
        float sq  = v.x*v.x + v.y*v.y + v.z*v.z + v.w*v.w;
        #pragma unroll
        for (int off = 32; off; off >>= 1) { sum += __shfl_xor(sum, off); sq += __shfl_xor(sq, off); }
        if ((t & 63) == 0) { s1[t >> 6] = sum; s2[t >> 6] = sq; }
        __syncthreads();
        sum = s1[0] + s1[1] + s1[2] + s1[3];
        sq  = s2[0] + s2[1] + s2[2] + s2[3];
        __syncthreads();
        float mu = sum * (1.f / GNN_DIM);
        float var = sq * (1.f / GNN_DIM) - mu * mu;
        float rstd = rsqrtf(var + 1e-5f);
        float y0 = fmaxf((v.x - mu) * rstd * gg.x + be.x, 0.f);
        float y1 = fmaxf((v.y - mu) * rstd * gg.y + be.y, 0.f);
        float y2 = fmaxf((v.z - mu) * rstd * gg.z + be.z, 0.f);
        float y3 = fmaxf((v.w - mu) * rstd * gg.w + be.w, 0.f);
        int2 pk;
        pk.x = pack2(f2bf(y0), f2bf(y1));
        pk.y = pack2(f2bf(y2), f2bf(y3));
        *(int2*)(g_h + (size_t)n * GNN_DIM + t * 4) = pk;
    }
}

// ---------------------------------------------------------------------------
// Layer 2 aggregation: agg2[n] = mean of h[src] rows.
// Full row per wave (2 int4/lane), masked 8-edge batches -> 16 independent
// 1KB requests in flight per wave.
// ---------------------------------------------------------------------------
__global__ __launch_bounds__(256) void l2_agg_kernel() {
    int w = threadIdx.x >> 6, lane = threadIdx.x & 63;
    int n = blockIdx.x * 4 + w;              // 12500 blocks * 4 = 50000 exact
    int beg = g_rowptr[n], end = g_rowptr[n + 1];
    float s[16];
    #pragma unroll
    for (int j = 0; j < 16; ++j) s[j] = 0.f;
    const int4* hp = (const int4*)g_h;       // row = 128 int4
    for (int i = beg; i < end; i += 8) {
        int idx[8]; float msk[8]; int4 va[8], vb[8];
        #pragma unroll
        for (int j = 0; j < 8; ++j) {
            int e = i + j;
            int cl = (e < end) ? e : beg;    // beg valid since loop entered
            idx[j] = g_esrc[cl];
            msk[j] = (e < end) ? 1.f : 0.f;
        }
        #pragma unroll
        for (int j = 0; j < 8; ++j) {
            va[j] = hp[(size_t)idx[j] * 128 + lane];
            vb[j] = hp[(size_t)idx[j] * 128 + 64 + lane];
        }
        #pragma unroll
        for (int j = 0; j < 8; ++j) {
            float m = msk[j];
            s[0]  += m * bflo(va[j].x); s[1]  += m * bfhi(va[j].x);
            s[2]  += m * bflo(va[j].y); s[3]  += m * bfhi(va[j].y);
            s[4]  += m * bflo(va[j].z); s[5]  += m * bfhi(va[j].z);
            s[6]  += m * bflo(va[j].w); s[7]  += m * bfhi(va[j].w);
            s[8]  += m * bflo(vb[j].x); s[9]  += m * bfhi(vb[j].x);
            s[10] += m * bflo(vb[j].y); s[11] += m * bfhi(vb[j].y);
            s[12] += m * bflo(vb[j].z); s[13] += m * bfhi(vb[j].z);
            s[14] += m * bflo(vb[j].w); s[15] += m * bfhi(vb[j].w);
        }
    }
    float inv = 1.f / (float)max(end - beg, 1);
    int4 o0, o1;
    o0.x = pack2(f2bf(s[0] * inv),  f2bf(s[1] * inv));
    o0.y = pack2(f2bf(s[2] * inv),  f2bf(s[3] * inv));
    o0.z = pack2(f2bf(s[4] * inv),  f2bf(s[5] * inv));
    o0.w = pack2(f2bf(s[6] * inv),  f2bf(s[7] * inv));
    o1.x = pack2(f2bf(s[8] * inv),  f2bf(s[9] * inv));
    o1.y = pack2(f2bf(s[10] * inv), f2bf(s[11] * inv));
    o1.z = pack2(f2bf(s[12] * inv), f2bf(s[13] * inv));
    o1.w = pack2(f2bf(s[14] * inv), f2bf(s[15] * inv));
    *(int4*)(g_agg2 + (size_t)n * GNN_DIM + (size_t)lane * 8) = o0;
    *(int4*)(g_agg2 + (size_t)n * GNN_DIM + 512 + (size_t)lane * 8) = o1;
}

// ---------------------------------------------------------------------------
// Layer 2 GEMM: h2 = agg2 @ W2_l + h @ W2_r + b2  (bf16 MFMA)
// XCD-bijective tile remap + XOR swizzle; clean bias+store epilogue.
// (R6-measured: 237 us, 888 TF, 0 bank conflicts)
// ---------------------------------------------------------------------------
#define BM 128
#define BN 128
#define BK 64

__global__ __launch_bounds__(256) void gemm2_kernel(const float* __restrict__ bias) {
    __shared__ __attribute__((aligned(16))) unsigned short As[BM * BK];
    __shared__ __attribute__((aligned(16))) unsigned short Bs[BN * BK];
    int i = blockIdx.x;
    int xcd = i & 7;
    int j = i >> 3;                 // 0..391
    int bm = xcd * 49 + (j >> 3);   // 0..391
    int bn = j & 7;
    int row0 = bm * BM, col0 = bn * BN;
    int t = threadIdx.x;
    int lane = t & 63, wid = t >> 6;
    int wr = wid >> 1, wc = wid & 1;     // 2x2 waves, each owns 64x64
    f32x4 acc[4][4] = {};
    int c0 = t;
    for (int seg = 0; seg < 2; ++seg) {
        const unsigned short* A  = seg ? g_h : g_agg2;
        const unsigned short* Bt = seg ? g_w2rt : g_w2lt;
        for (int k0 = 0; k0 < GNN_DIM; k0 += BK) {
            __syncthreads();
            #pragma unroll
            for (int u = 0; u < 4; ++u) {
                int c = c0 + u * 256;
                int r = c >> 3;
                int kb = (c & 7) * 16;                  // byte offset within row
                int kbs = kb ^ ((r & 7) << 4);          // inverse-swizzled source
                __builtin_amdgcn_global_load_lds(
                    (const __attribute__((address_space(1))) void*)(A + (size_t)(row0 + r) * GNN_DIM + k0 + (kbs >> 1)),
                    (__attribute__((address_space(3))) void*)(As + c * 8), 16, 0, 0);
            }
            #pragma unroll
            for (int u = 0; u < 4; ++u) {
                int c = c0 + u * 256;
                int r = c >> 3;
                int kb = (c & 7) * 16;
                int kbs = kb ^ ((r & 7) << 4);
                __builtin_amdgcn_global_load_lds(
                    (const __attribute__((address_space(1))) void*)(Bt + (size_t)(col0 + r) * GNN_DIM + k0 + (kbs >> 1)),
                    (__attribute__((address_space(3))) void*)(Bs + c * 8), 16, 0, 0);
            }
            asm volatile("s_waitcnt vmcnt(0)" ::: "memory");
            __syncthreads();
            #pragma unroll
            for (int kk = 0; kk < BK; kk += 32) {
                short8 a[4], b[4];
                int krd = kk + (lane >> 4) * 8;          // short index in row
                #pragma unroll
                for (int m = 0; m < 4; ++m) {
                    int row = wr * 64 + m * 16 + (lane & 15);
                    int ks = ((krd * 2) ^ ((row & 7) << 4)) >> 1;   // swizzled read
                    a[m] = *(const short8*)&As[row * BK + ks];
                }
                #pragma unroll
                for (int n = 0; n < 4; ++n) {
                    int row = wc * 64 + n * 16 + (lane & 15);
                    int ks = ((krd * 2) ^ ((row & 7) << 4)) >> 1;
                    b[n] = *(const short8*)&Bs[row * BK + ks];
                }
                #pragma unroll
                for (int m = 0; m < 4; ++m)
                    #pragma unroll
                    for (int n = 0; n < 4; ++n)
                        acc[m][n] = __builtin_amdgcn_mfma_f32_16x16x32_bf16(a[m], b[n], acc[m][n], 0, 0, 0);
            }
        }
    }
    #pragma unroll
    for (int m = 0; m < 4; ++m) {
        #pragma unroll
        for (int n = 0; n < 4; ++n) {
            int col = col0 + wc * 64 + n * 16 + (lane & 15);
            int rbase = row0 + wr * 64 + m * 16 + (lane >> 4) * 4;
            float bv = bias[col];
            #pragma unroll
            for (int r = 0; r < 4; ++r) {
                float v = acc[m][n][r] + bv;
                g_h2[(size_t)(rbase + r) * GNN_DIM + col] = f2bf(v);
            }
        }
    }
}

// ---------------------------------------------------------------------------
// Pool (h part): per node compute LN stats in-block (block sees full row),
// apply LN+ReLU, accumulate per graph. grid = 64 graphs * 8 node-slices.
// ---------------------------------------------------------------------------
__global__ __launch_bounds__(256) void pool_h_kernel(const float* __restrict__ g2,
                                                     const float* __restrict__ be2) {
    int g = blockIdx.x >> 3, sl = blockIdx.x & 7;
    int t = threadIdx.x;
    int beg = g_goff[g], end = g_goff[g + 1];
    int cnt = end - beg;
    int per = (cnt + 7) >> 3;
    int s0 = beg + sl * per, s1v = min(s0 + per, end);
    if (s0 >= s1v) return;                   // block-uniform
    float4 gg = *(const float4*)&g2[t * 4];
    float4 be = *(const float4*)&be2[t * 4];
    __shared__ float r1[4], r2[4];
    float a0 = 0.f, a1 = 0.f, a2 = 0.f, a3 = 0.f;
    int2 wv = *(const int2*)(g_h2 + (size_t)s0 * GNN_DIM + t * 4);
    for (int n = s0; n < s1v; ++n) {
        int2 w = wv;
        if (n + 1 < s1v) wv = *(const int2*)(g_h2 + (size_t)(n + 1) * GNN_DIM + t * 4);
        float v0 = bflo(w.x), v1 = bfhi(w.x), v2 = bflo(w.y), v3 = bfhi(w.y);
        float sum = v0 + v1 + v2 + v3;
        float sq  = v0*v0 + v1*v1 + v2*v2 + v3*v3;
        #pragma unroll
        for (int off = 32; off; off >>= 1) { sum += __shfl_xor(sum, off); sq += __shfl_xor(sq, off); }
        if ((t & 63) == 0) { r1[t >> 6] = sum; r2[t >> 6] = sq; }
        __syncthreads();
        sum = r1[0] + r1[1] + r1[2] + r1[3];
        sq  = r2[0] + r2[1] + r2[2] + r2[3];
        __syncthreads();
        float mu = sum * (1.f / GNN_DIM);
        float var = sq * (1.f / GNN_DIM) - mu * mu;
        float rstd = rsqrtf(var + 1e-5f);
        a0 += fmaxf((v0 - mu) * rstd * gg.x + be.x, 0.f);
        a1 += fmaxf((v1 - mu) * rstd * gg.y + be.y, 0.f);
        a2 += fmaxf((v2 - mu) * rstd * gg.z + be.z, 0.f);
        a3 += fmaxf((v3 - mu) * rstd * gg.w + be.w, 0.f);
    }
    atomicAdd(&g_gpool[g * CAT_DIM + t * 4 + 0], a0);
    atomicAdd(&g_gpool[g * CAT_DIM + t * 4 + 1], a1);
    atomicAdd(&g_gpool[g * CAT_DIM + t * 4 + 2], a2);
    atomicAdd(&g_gpool[g * CAT_DIM + t * 4 + 3], a3);
}

// ---------------------------------------------------------------------------
// Pool (fourier part): coords staged in LDS; thread handles 2 (scale,c)
// pairs, one proj shared by sin+cos. grid = 64 graphs * 4 node-slices.
// ---------------------------------------------------------------------------
__global__ __launch_bounds__(256) void pool_f_kernel(const float* __restrict__ coords,
                                                     const float* __restrict__ Bmat) {
    int g = blockIdx.x >> 2, sl = blockIdx.x & 3;
    int t = threadIdx.x;
    int beg = g_goff[g], end = g_goff[g + 1];
    int cnt = end - beg;
    int per = (cnt + 3) >> 2;
    int s0 = beg + sl * per, s1 = min(s0 + per, end);
    const float SC[4] = {1.f, 5.f, 10.f, 30.f};
    int si0 = t >> 7, c0 = t & 127;        // scales 0,1
    int si1 = si0 + 2;                     // scales 2,3
    float b00 = Bmat[c0] * SC[si0], b01 = Bmat[128 + c0] * SC[si0], b02 = Bmat[256 + c0] * SC[si0];
    float b10 = Bmat[c0] * SC[si1], b11 = Bmat[128 + c0] * SC[si1], b12 = Bmat[256 + c0] * SC[si1];
    float ss0 = 0.f, cs0 = 0.f, ss1 = 0.f, cs1 = 0.f;
    __shared__ float sc[256 * 3];
    for (int base = s0; base < s1; base += 256) {
        int m = min(256, s1 - base);
        __syncthreads();
        for (int q = t; q < 3 * m; q += 256) sc[q] = coords[base * 3 + q];
        __syncthreads();
        for (int i = 0; i < m; ++i) {
            float x0 = sc[i * 3], y0 = sc[i * 3 + 1], z0 = sc[i * 3 + 2];
            float p0 = x0 * b00 + y0 * b01 + z0 * b02;
            float p1 = x0 * b10 + y0 * b11 + z0 * b12;
            ss0 += __sinf(p0); cs0 += __cosf(p0);
            ss1 += __sinf(p1); cs1 += __cosf(p1);
        }
    }
    if (s0 < s1) {
        float* gp = g_gpool + g * CAT_DIM + GNN_DIM;
        atomicAdd(&gp[si0 * 256 + c0], ss0);
        atomicAdd(&gp[si0 * 256 + 128 + c0], cs0);
        atomicAdd(&gp[si1 * 256 + c0], ss1);
        atomicAdd(&gp[si1 * 256 + 128 + c0], cs1);
    }
}

// ---------------------------------------------------------------------------
// Final: out = LN(gpool/cnt @ Wfc + bfc)   (64 blocks x 256 threads)
// ---------------------------------------------------------------------------
__global__ __launch_bounds__(256) void final_kernel(
        const float* __restrict__ Wfc, const float* __restrict__ bfc,
        const float* __restrict__ gfc, const float* __restrict__ befc,
        float* __restrict__ out) {
    int g = blockIdx.x, t = threadIdx.x;
    int beg = g_goff[g], end = g_goff[g + 1];
    float inv = 1.f / (float)max(end - beg, 1);
    __shared__ float hg[CAT_DIM];
    for (int i = t; i < CAT_DIM; i += 256) hg[i] = g_gpool[g * CAT_DIM + i] * inv;
    __syncthreads();
    float acc = bfc[t];
    for (int k = 0; k < CAT_DIM; ++k) acc = fmaf(hg[k], Wfc[(size_t)k * OUT_DIM + t], acc);
    float sum = acc, sq = acc * acc;
    #pragma unroll
    for (int off = 32; off; off >>= 1) { sum += __shfl_xor(sum, off); sq += __shfl_xor(sq, off); }
    __shared__ float s1[4], s2[4];
    if ((t & 63) == 0) { s1[t >> 6] = sum; s2[t >> 6] = sq; }
    __syncthreads();
    sum = s1[0] + s1[1] + s1[2] + s1[3];
    sq  = s2[0] + s2[1] + s2[2] + s2[3];
    float mu = sum * (1.f / OUT_DIM);
    float var = sq * (1.f / OUT_DIM) - mu * mu;
    float rstd = rsqrtf(var + 1e-5f);
    out[g * OUT_DIM + t] = (acc - mu) * rstd * gfc[t] + befc[t];
}

// ---------------------------------------------------------------------------
extern "C" void kernel_launch(void* const* d_in, const int* in_sizes, int n_in,
                              void* d_out, int out_size, void* d_ws, size_t ws_size,
                              hipStream_t stream) {
    const float* x      = (const float*)d_in[0];
    const int*   ei     = (const int*)d_in[1];
    const float* coords = (const float*)d_in[2];
    const int*   batch  = (const int*)d_in[3];
    const float* Bmat   = (const float*)d_in[4];
    const float* W1l    = (const float*)d_in[5];
    const float* b1     = (const float*)d_in[6];
    const float* W1r    = (const float*)d_in[7];
    const float* g1     = (const float*)d_in[8];
    const float* be1    = (const float*)d_in[9];
    const float* W2l    = (const float*)d_in[10];
    const float* b2     = (const float*)d_in[11];
    const float* W2r    = (const float*)d_in[12];
    const float* g2     = (const float*)d_in[13];
    const float* be2    = (const float*)d_in[14];
    const float* Wfc    = (const float*)d_in[15];
    const float* bfc    = (const float*)d_in[16];
    const float* gfc    = (const float*)d_in[17];
    const float* befc   = (const float*)d_in[18];
    const int* src = ei;
    const int* dst = ei + N_EDGES;
    float* out = (float*)d_out;
    (void)in_sizes; (void)n_in; (void)out_size; (void)d_ws; (void)ws_size;

    unsigned short* w2lt;  hipGetSymbolAddress((void**)&w2lt, HIP_SYMBOL(g_w2lt));
    unsigned short* w2rt;  hipGetSymbolAddress((void**)&w2rt, HIP_SYMBOL(g_w2rt));

    zero_kernel<<<512, 256, 0, stream>>>();
    count_kernel<<<(N_EDGES + 255) / 256, 256, 0, stream>>>(dst, batch);
    scan_kernel<<<1, 1024, 0, stream>>>();
    scatter_kernel<<<(N_EDGES + 255) / 256, 256, 0, stream>>>(src, dst);

    transpose_bf16<<<2048, 256, 0, stream>>>(W2l, W2r, w2lt, w2rt);

    l1_agg_kernel<<<(N_NODES * 8 + 255) / 256, 256, 0, stream>>>(x);
    l1_transform_kernel<<<N_NODES / 8, 256, 0, stream>>>(x, W1l, b1, W1r, g1, be1);

    l2_agg_kernel<<<N_NODES / 4, 256, 0, stream>>>();

    gemm2_kernel<<<(M_PAD / BM) * (GNN_DIM / BN), 256, 0, stream>>>(b2);

    pool_h_kernel<<<N_GRAPHS * 8, 256, 0, stream>>>(g2, be2);
    pool_f_kernel<<<N_GRAPHS * 4, 256, 0, stream>>>(coords, Bmat);

    final_kernel<<<N_GRAPHS, 256, 0, stream>>>(Wfc, bfc, gfc, befc, out);
}

// Round 9
// 800.700 us; speedup vs baseline: 1.1597x; 1.1064x over previous
//
#include <hip/hip_runtime.h>
#include <hip/hip_bf16.h>

// ---------------------------------------------------------------------------
// GraphEncoder: SAGE(6->1024) -> LN -> ReLU -> SAGE(1024->1024) -> LN -> ReLU
//   -> concat(Fourier feats) -> per-graph mean pool -> FC(2048->256) -> LN
// gemm2: 128x128 m97-structure (888 TF measured). l2_agg gathers an fp8
// side-copy of h (halves the 1 GB gather). pool_h is wave-per-node.
// ---------------------------------------------------------------------------

#define N_NODES 50000
#define N_EDGES 500000
#define N_GRAPHS 64
#define IN_DIM 6
#define GNN_DIM 1024
#define OUT_DIM 256
#define CAT_DIM 2048
#define M_PAD 50176   // 392 * 128  (392 = 8 XCDs * 49 row-groups)

typedef __attribute__((ext_vector_type(8))) short short8;
typedef __attribute__((ext_vector_type(4))) float f32x4;

#if defined(__has_builtin)
#if __has_builtin(__builtin_amdgcn_cvt_pk_fp8_f32) && __has_builtin(__builtin_amdgcn_cvt_pk_f32_fp8)
#define HW_FP8 1
#endif
#endif

// ---------------- static device scratch (allocated at module load) ---------
__device__ int g_cnt[N_NODES + 1];
__device__ int g_cursor[N_NODES];
__device__ int g_gcnt[N_GRAPHS];
__device__ int g_rowptr[N_NODES + 1];
__device__ int g_goff[N_GRAPHS + 1];
__device__ int g_esrc[N_EDGES];
__device__ __attribute__((aligned(256))) unsigned short g_w2lt[(size_t)GNN_DIM * GNN_DIM];
__device__ __attribute__((aligned(256))) unsigned short g_w2rt[(size_t)GNN_DIM * GNN_DIM];
__device__ float g_agg1[(size_t)N_NODES * IN_DIM];
__device__ __attribute__((aligned(256))) unsigned short g_h[(size_t)M_PAD * GNN_DIM];
__device__ __attribute__((aligned(256))) unsigned g_h8w[(size_t)M_PAD * (GNN_DIM / 4)];
__device__ __attribute__((aligned(256))) unsigned short g_agg2[(size_t)M_PAD * GNN_DIM];
__device__ __attribute__((aligned(256))) unsigned short g_h2[(size_t)M_PAD * GNN_DIM];
__device__ float g_gpool[(size_t)N_GRAPHS * CAT_DIM];

__device__ __forceinline__ float bflo(int u) { return __uint_as_float(((unsigned)u) << 16); }
__device__ __forceinline__ float bfhi(int u) { return __uint_as_float(((unsigned)u) & 0xffff0000u); }
__device__ __forceinline__ unsigned short f2bf(float f) {
    unsigned u = __float_as_uint(f);
    unsigned rounded = u + 0x7fff + ((u >> 16) & 1);   // RNE
    return (unsigned short)(rounded >> 16);
}
__device__ __forceinline__ int pack2(unsigned short a, unsigned short b) {
    return (int)((unsigned)a | ((unsigned)b << 16));
}

#ifndef HW_FP8
// software e4m3 codec (FTZ, RNE, clamp 448); inputs are >=0 (post-ReLU)
__device__ __forceinline__ unsigned enc8(float f) {
    if (!(f >= 0.015625f)) return 0;     // below min normal -> 0
    if (f > 448.f) f = 448.f;
    unsigned u = __float_as_uint(f);
    u += 0x7FFFF + ((u >> 20) & 1);      // RNE at bit 20
    unsigned e = (u >> 23) & 0xFF;
    return ((e - 120) << 3) | ((u >> 20) & 7);
}
__device__ __forceinline__ float dec8(unsigned b) {
    unsigned e = (b >> 3) & 15, m = b & 7;
    unsigned f = ((e + 120) << 23) | (m << 20);
    return e ? __uint_as_float(f) : 0.f;
}
#endif

// ---------------------------------------------------------------------------
// zero + CSR build
// ---------------------------------------------------------------------------
__global__ void zero_kernel() {          // grid 512 -> 131072 threads
    int i = blockIdx.x * 256 + threadIdx.x;
    if (i <= N_NODES) g_cnt[i] = 0;
    if (i < N_NODES) g_cursor[i] = 0;
    if (i < N_GRAPHS) g_gcnt[i] = 0;
    if (i < N_GRAPHS * CAT_DIM) g_gpool[i] = 0.f;
}

__global__ void count_kernel(const int* __restrict__ dst, const int* __restrict__ batch) {
    int i = blockIdx.x * 256 + threadIdx.x;
    if (i < N_EDGES) atomicAdd(&g_cnt[dst[i]], 1);
    if (i < N_NODES) atomicAdd(&g_gcnt[batch[i]], 1);
}

// two-level scan (rowptr) + graph-offset prefix (goff) in one kernel
__global__ __launch_bounds__(1024) void scan_kernel() {
    const int CH = 49;           // 1024 * 49 = 50176 >= N_NODES+1
    int t = threadIdx.x;
    int base = t * CH;
    int s = 0;
    #pragma unroll
    for (int i = 0; i < CH; ++i) {
        int n = base + i;
        s += (n < N_NODES) ? g_cnt[n] : 0;
    }
    int lane = t & 63, w = t >> 6;
    int x = s;
    #pragma unroll
    for (int off = 1; off < 64; off <<= 1) {
        int y = __shfl_up(x, off);
        if (lane >= off) x += y;
    }
    __shared__ int wsum[16], woff[16];
    if (lane == 63) wsum[w] = x;
    __syncthreads();
    if (t == 0) { int a = 0; for (int i = 0; i < 16; ++i) { woff[i] = a; a += wsum[i]; } }
    __syncthreads();
    int excl = x - s + woff[w];      // exclusive prefix at chunk start
    #pragma unroll
    for (int i = 0; i < CH; ++i) {
        int n = base + i;
        if (n <= N_NODES) g_rowptr[n] = excl;
        if (n < N_NODES) excl += g_cnt[n];
    }
    // goff: 64-thread wave prefix over g_gcnt
    if (t < 64) {
        int v = g_gcnt[t];
        int xx = v;
        #pragma unroll
        for (int off = 1; off < 64; off <<= 1) {
            int y = __shfl_up(xx, off);
            if ((t & 63) >= off) xx += y;
        }
        g_goff[t + 1] = xx;
        if (t == 0) g_goff[0] = 0;
    }
}

__global__ void scatter_kernel(const int* __restrict__ src, const int* __restrict__ dst) {
    int e = blockIdx.x * 256 + threadIdx.x;
    if (e >= N_EDGES) return;
    int d = dst[e];
    int pos = atomicAdd(&g_cursor[d], 1);
    g_esrc[g_rowptr[d] + pos] = src[e];
}

// ---------------------------------------------------------------------------
// Weight transpose f32 [K][N] -> bf16 [N][K], both weights in one dispatch
// ---------------------------------------------------------------------------
__global__ void transpose_bf16(const float* __restrict__ WA, const float* __restrict__ WB,
                               unsigned short* __restrict__ TA, unsigned short* __restrict__ TB) {
    __shared__ float tile[32][33];
    int id = blockIdx.x & 1023;
    const float* W = (blockIdx.x >> 10) ? WB : WA;
    unsigned short* Wt = (blockIdx.x >> 10) ? TB : TA;
    int bx = id & 31, by = id >> 5;
    int tx = threadIdx.x & 31, ty = threadIdx.x >> 5;  // 32x8
    for (int i = 0; i < 32; i += 8)
        tile[ty + i][tx] = W[(size_t)(by * 32 + ty + i) * GNN_DIM + bx * 32 + tx];
    __syncthreads();
    for (int i = 0; i < 32; i += 8)
        Wt[(size_t)(bx * 32 + ty + i) * GNN_DIM + by * 32 + tx] = f2bf(tile[tx][ty + i]);
}

// ---------------------------------------------------------------------------
// Layer 1: mean-agg of x (6-dim), transform, LN, ReLU -> h (bf16) + h8 (fp8)
// ---------------------------------------------------------------------------
__global__ void l1_agg_kernel(const float* __restrict__ x) {
    int id = blockIdx.x * 256 + threadIdx.x;
    int n = id >> 3, slot = id & 7;
    if (n >= N_NODES || slot >= IN_DIM) return;
    int beg = g_rowptr[n], end = g_rowptr[n + 1];
    float s = 0.f;
    for (int i = beg; i < end; ++i) s += x[(size_t)g_esrc[i] * IN_DIM + slot];
    g_agg1[n * IN_DIM + slot] = s / (float)max(end - beg, 1);
}

// 8 nodes per block; weights held in registers (dims t*4..t*4+3 per thread)
__global__ __launch_bounds__(256) void l1_transform_kernel(
        const float* __restrict__ x,
        const float* __restrict__ W1l, const float* __restrict__ b1,
        const float* __restrict__ W1r, const float* __restrict__ g1,
        const float* __restrict__ be1) {
    int t = threadIdx.x;
    int nb = blockIdx.x * 8;                 // 6250 blocks * 8 = 50000 exact
    float4 wl[6], wr[6];
    #pragma unroll
    for (int k = 0; k < 6; ++k) {
        wl[k] = *(const float4*)&W1l[k * GNN_DIM + t * 4];
        wr[k] = *(const float4*)&W1r[k * GNN_DIM + t * 4];
    }
    float4 bb = *(const float4*)&b1[t * 4];
    float4 gg = *(const float4*)&g1[t * 4];
    float4 be = *(const float4*)&be1[t * 4];
    __shared__ float sx[48], sa[48];
    if (t < 48) sx[t] = x[nb * 6 + t];
    else if (t < 96) sa[t - 48] = g_agg1[nb * 6 + (t - 48)];
    __syncthreads();
    __shared__ float s1[4], s2[4];
    for (int u = 0; u < 8; ++u) {
        int n = nb + u;
        float4 v = bb;
        #pragma unroll
        for (int k = 0; k < 6; ++k) {
            float a = sa[u * 6 + k], xx = sx[u * 6 + k];
            v.x += a * wl[k].x + xx * wr[k].x;
            v.y += a * wl[k].y + xx * wr[k].y;
            v.z += a * wl[k].z + xx * wr[k].z;
            v.w += a * wl[k].w + xx * wr[k].w;
        }
        float sum = v.x + v.y + v.z + v.w;
        float sq  = v.x*v.x + v.y*v.y + v.z*v.z + v.w*v.w;
        #pragma unroll
        for (int off = 32; off; off >>= 1) { sum += __shfl_xor(sum, off); sq += __shfl_xor(sq, off); }
        if ((t & 63) == 0) { s1[t >> 6] = sum; s2[t >> 6] = sq; }
        __syncthreads();
        sum = s1[0] + s1[1] + s1[2] + s1[3];
        sq  = s2[0] + s2[1] + s2[2] + s2[3];
        __syncthreads();
        float mu = sum * (1.f / GNN_DIM);
        float var = sq * (1.f / GNN_DIM) - mu * mu;
        float rstd = rsqrtf(var + 1e-5f);
        float y0 = fmaxf((v.x - mu) * rstd * gg.x + be.x, 0.f);
        float y1 = fmaxf((v.y - mu) * rstd * gg.y + be.y, 0.f);
        float y2 = fmaxf((v.z - mu) * rstd * gg.z + be.z, 0.f);
        float y3 = fmaxf((v.w - mu) * rstd * gg.w + be.w, 0.f);
        int2 pk;
        pk.x = pack2(f2bf(y0), f2bf(y1));
        pk.y = pack2(f2bf(y2), f2bf(y3));
        *(int2*)(g_h + (size_t)n * GNN_DIM + t * 4) = pk;
#ifdef HW_FP8
        int p8 = __builtin_amdgcn_cvt_pk_fp8_f32(y0, y1, 0, false);
        p8 = __builtin_amdgcn_cvt_pk_fp8_f32(y2, y3, p8, true);
        g_h8w[(size_t)n * 256 + t] = (unsigned)p8;
#else
        g_h8w[(size_t)n * 256 + t] =
            enc8(y0) | (enc8(y1) << 8) | (enc8(y2) << 16) | (enc8(y3) << 24);
#endif
    }
}

// ---------------------------------------------------------------------------
// Layer 2 aggregation: agg2[n] = mean of h8[src] rows (fp8 gather, half the
// bytes of bf16). Wave-per-node; 1 int4/lane = full 1KB row; 8-edge batches.
// ---------------------------------------------------------------------------
#ifdef HW_FP8
#define DEC_ACC(word, b) do { \
    auto p0_ = __builtin_amdgcn_cvt_pk_f32_fp8((int)(word), false); \
    auto p1_ = __builtin_amdgcn_cvt_pk_f32_fp8((int)(word), true);  \
    s[(b)+0] += m * p0_[0]; s[(b)+1] += m * p0_[1]; \
    s[(b)+2] += m * p1_[0]; s[(b)+3] += m * p1_[1]; } while (0)
#else
#define DEC_ACC(word, b) do { unsigned w_ = (unsigned)(word); \
    s[(b)+0] += m * dec8(w_ & 255);        s[(b)+1] += m * dec8((w_ >> 8) & 255); \
    s[(b)+2] += m * dec8((w_ >> 16) & 255); s[(b)+3] += m * dec8(w_ >> 24); } while (0)
#endif

__global__ __launch_bounds__(256) void l2_agg_kernel() {
    int w = threadIdx.x >> 6, lane = threadIdx.x & 63;
    int n = blockIdx.x * 4 + w;              // 12500 blocks * 4 = 50000 exact
    int beg = g_rowptr[n], end = g_rowptr[n + 1];
    float s[16];
    #pragma unroll
    for (int j = 0; j < 16; ++j) s[j] = 0.f;
    const int4* hp = (const int4*)g_h8w;     // row = 64 int4 (1 KB)
    for (int i = beg; i < end; i += 8) {
        int idx[8]; float msk[8]; int4 v[8];
        #pragma unroll
        for (int j = 0; j < 8; ++j) {
            int e = i + j;
            int cl = (e < end) ? e : beg;    // beg valid since loop entered
            idx[j] = g_esrc[cl];
            msk[j] = (e < end) ? 1.f : 0.f;
        }
        #pragma unroll
        for (int j = 0; j < 8; ++j) v[j] = hp[(size_t)idx[j] * 64 + lane];
        #pragma unroll
        for (int j = 0; j < 8; ++j) {
            float m = msk[j];
            DEC_ACC(v[j].x, 0); DEC_ACC(v[j].y, 4);
            DEC_ACC(v[j].z, 8); DEC_ACC(v[j].w, 12);
        }
    }
    float inv = 1.f / (float)max(end - beg, 1);
    int4 o0, o1;
    o0.x = pack2(f2bf(s[0] * inv),  f2bf(s[1] * inv));
    o0.y = pack2(f2bf(s[2] * inv),  f2bf(s[3] * inv));
    o0.z = pack2(f2bf(s[4] * inv),  f2bf(s[5] * inv));
    o0.w = pack2(f2bf(s[6] * inv),  f2bf(s[7] * inv));
    o1.x = pack2(f2bf(s[8] * inv),  f2bf(s[9] * inv));
    o1.y = pack2(f2bf(s[10] * inv), f2bf(s[11] * inv));
    o1.z = pack2(f2bf(s[12] * inv), f2bf(s[13] * inv));
    o1.w = pack2(f2bf(s[14] * inv), f2bf(s[15] * inv));
    // lane owns dims 16*lane .. 16*lane+15
    *(int4*)(g_agg2 + (size_t)n * GNN_DIM + (size_t)lane * 16) = o0;
    *(int4*)(g_agg2 + (size_t)n * GNN_DIM + (size_t)lane * 16 + 8) = o1;
}

// ---------------------------------------------------------------------------
// Layer 2 GEMM: h2 = agg2 @ W2_l + h @ W2_r + b2  (bf16 MFMA)
// XCD-bijective tile remap + XOR swizzle; clean bias+store epilogue.
// (R6-measured: 237 us, 888 TF, 0 bank conflicts)
// ---------------------------------------------------------------------------
#define BM 128
#define BN 128
#define BK 64

__global__ __launch_bounds__(256) void gemm2_kernel(const float* __restrict__ bias) {
    __shared__ __attribute__((aligned(16))) unsigned short As[BM * BK];
    __shared__ __attribute__((aligned(16))) unsigned short Bs[BN * BK];
    int i = blockIdx.x;
    int xcd = i & 7;
    int j = i >> 3;                 // 0..391
    int bm = xcd * 49 + (j >> 3);   // 0..391
    int bn = j & 7;
    int row0 = bm * BM, col0 = bn * BN;
    int t = threadIdx.x;
    int lane = t & 63, wid = t >> 6;
    int wr = wid >> 1, wc = wid & 1;     // 2x2 waves, each owns 64x64
    f32x4 acc[4][4] = {};
    int c0 = t;
    for (int seg = 0; seg < 2; ++seg) {
        const unsigned short* A  = seg ? g_h : g_agg2;
        const unsigned short* Bt = seg ? g_w2rt : g_w2lt;
        for (int k0 = 0; k0 < GNN_DIM; k0 += BK) {
            __syncthreads();
            #pragma unroll
            for (int u = 0; u < 4; ++u) {
                int c = c0 + u * 256;
                int r = c >> 3;
                int kb = (c & 7) * 16;                  // byte offset within row
                int kbs = kb ^ ((r & 7) << 4);          // inverse-swizzled source
                __builtin_amdgcn_global_load_lds(
                    (const __attribute__((address_space(1))) void*)(A + (size_t)(row0 + r) * GNN_DIM + k0 + (kbs >> 1)),
                    (__attribute__((address_space(3))) void*)(As + c * 8), 16, 0, 0);
            }
            #pragma unroll
            for (int u = 0; u < 4; ++u) {
                int c = c0 + u * 256;
                int r = c >> 3;
                int kb = (c & 7) * 16;
                int kbs = kb ^ ((r & 7) << 4);
                __builtin_amdgcn_global_load_lds(
                    (const __attribute__((address_space(1))) void*)(Bt + (size_t)(col0 + r) * GNN_DIM + k0 + (kbs >> 1)),
                    (__attribute__((address_space(3))) void*)(Bs + c * 8), 16, 0, 0);
            }
            asm volatile("s_waitcnt vmcnt(0)" ::: "memory");
            __syncthreads();
            #pragma unroll
            for (int kk = 0; kk < BK; kk += 32) {
                short8 a[4], b[4];
                int krd = kk + (lane >> 4) * 8;          // short index in row
                #pragma unroll
                for (int m = 0; m < 4; ++m) {
                    int row = wr * 64 + m * 16 + (lane & 15);
                    int ks = ((krd * 2) ^ ((row & 7) << 4)) >> 1;   // swizzled read
                    a[m] = *(const short8*)&As[row * BK + ks];
                }
                #pragma unroll
                for (int n = 0; n < 4; ++n) {
                    int row = wc * 64 + n * 16 + (lane & 15);
                    int ks = ((krd * 2) ^ ((row & 7) << 4)) >> 1;
                    b[n] = *(const short8*)&Bs[row * BK + ks];
                }
                #pragma unroll
                for (int m = 0; m < 4; ++m)
                    #pragma unroll
                    for (int n = 0; n < 4; ++n)
                        acc[m][n] = __builtin_amdgcn_mfma_f32_16x16x32_bf16(a[m], b[n], acc[m][n], 0, 0, 0);
            }
        }
    }
    #pragma unroll
    for (int m = 0; m < 4; ++m) {
        #pragma unroll
        for (int n = 0; n < 4; ++n) {
            int col = col0 + wc * 64 + n * 16 + (lane & 15);
            int rbase = row0 + wr * 64 + m * 16 + (lane >> 4) * 4;
            float bv = bias[col];
            #pragma unroll
            for (int r = 0; r < 4; ++r) {
                float v = acc[m][n][r] + bv;
                g_h2[(size_t)(rbase + r) * GNN_DIM + col] = f2bf(v);
            }
        }
    }
}

// ---------------------------------------------------------------------------
// Pool (h part): wave-per-node LN stats (shfl only, no barriers), LN+ReLU,
// per-lane register accumulators; LDS merge + 1024 atomics per block.
// grid = 64 graphs * 8 node-slices; block = 4 waves.
// ---------------------------------------------------------------------------
__global__ __launch_bounds__(256) void pool_h_kernel(const float* __restrict__ g2,
                                                     const float* __restrict__ be2) {
    int g = blockIdx.x >> 3, sl = blockIdx.x & 7;
    int t = threadIdx.x;
    int w = t >> 6, lane = t & 63;
    int beg = g_goff[g], end = g_goff[g + 1];
    int cnt = end - beg;
    int per = (cnt + 7) >> 3;
    int s0 = beg + sl * per, s1v = min(s0 + per, end);
    // lane owns dims dA = 8*lane..+7 and dB = 512+8*lane..+7
    float gA[8], bA[8], gB[8], bB[8];
    #pragma unroll
    for (int j = 0; j < 8; ++j) {
        gA[j] = g2[8 * lane + j];        bA[j] = be2[8 * lane + j];
        gB[j] = g2[512 + 8 * lane + j];  bB[j] = be2[512 + 8 * lane + j];
    }
    float aA[8], aB[8];
    #pragma unroll
    for (int j = 0; j < 8; ++j) { aA[j] = 0.f; aB[j] = 0.f; }
    for (int n = s0 + w; n < s1v; n += 4) {
        const int4* rp = (const int4*)(g_h2 + (size_t)n * GNN_DIM);
        int4 w0 = rp[lane], w1 = rp[64 + lane];
        float vA[8] = { bflo(w0.x), bfhi(w0.x), bflo(w0.y), bfhi(w0.y),
                        bflo(w0.z), bfhi(w0.z), bflo(w0.w), bfhi(w0.w) };
        float vB[8] = { bflo(w1.x), bfhi(w1.x), bflo(w1.y), bfhi(w1.y),
                        bflo(w1.z), bfhi(w1.z), bflo(w1.w), bfhi(w1.w) };
        float sum = 0.f, sq = 0.f;
        #pragma unroll
        for (int j = 0; j < 8; ++j) {
            sum += vA[j] + vB[j];
            sq  += vA[j] * vA[j] + vB[j] * vB[j];
        }
        #pragma unroll
        for (int off = 32; off; off >>= 1) { sum += __shfl_xor(sum, off); sq += __shfl_xor(sq, off); }
        float mu = sum * (1.f / GNN_DIM);
        float var = sq * (1.f / GNN_DIM) - mu * mu;
        float rstd = rsqrtf(var + 1e-5f);
        #pragma unroll
        for (int j = 0; j < 8; ++j) {
            aA[j] += fmaxf((vA[j] - mu) * rstd * gA[j] + bA[j], 0.f);
            aB[j] += fmaxf((vB[j] - mu) * rstd * gB[j] + bB[j], 0.f);
        }
    }
    __shared__ float lacc[4][GNN_DIM];   // 16 KB
    #pragma unroll
    for (int j = 0; j < 8; ++j) {
        lacc[w][8 * lane + j] = aA[j];
        lacc[w][512 + 8 * lane + j] = aB[j];
    }
    __syncthreads();
    #pragma unroll
    for (int q = 0; q < 4; ++q) {
        int d = t * 4 + q;
        float r = lacc[0][d] + lacc[1][d] + lacc[2][d] + lacc[3][d];
        atomicAdd(&g_gpool[g * CAT_DIM + d], r);
    }
}

// ---------------------------------------------------------------------------
// Pool (fourier part): coords staged in LDS; thread handles 2 (scale,c)
// pairs, one proj shared by sin+cos. grid = 64 graphs * 4 node-slices.
// ---------------------------------------------------------------------------
__global__ __launch_bounds__(256) void pool_f_kernel(const float* __restrict__ coords,
                                                     const float* __restrict__ Bmat) {
    int g = blockIdx.x >> 2, sl = blockIdx.x & 3;
    int t = threadIdx.x;
    int beg = g_goff[g], end = g_goff[g + 1];
    int cnt = end - beg;
    int per = (cnt + 3) >> 2;
    int s0 = beg + sl * per, s1 = min(s0 + per, end);
    const float SC[4] = {1.f, 5.f, 10.f, 30.f};
    int si0 = t >> 7, c0 = t & 127;        // scales 0,1
    int si1 = si0 + 2;                     // scales 2,3
    float b00 = Bmat[c0] * SC[si0], b01 = Bmat[128 + c0] * SC[si0], b02 = Bmat[256 + c0] * SC[si0];
    float b10 = Bmat[c0] * SC[si1], b11 = Bmat[128 + c0] * SC[si1], b12 = Bmat[256 + c0] * SC[si1];
    float ss0 = 0.f, cs0 = 0.f, ss1 = 0.f, cs1 = 0.f;
    __shared__ float sc[256 * 3];
    for (int base = s0; base < s1; base += 256) {
        int m = min(256, s1 - base);
        __syncthreads();
        for (int q = t; q < 3 * m; q += 256) sc[q] = coords[base * 3 + q];
        __syncthreads();
        for (int i = 0; i < m; ++i) {
            float x0 = sc[i * 3], y0 = sc[i * 3 + 1], z0 = sc[i * 3 + 2];
            float p0 = x0 * b00 + y0 * b01 + z0 * b02;
            float p1 = x0 * b10 + y0 * b11 + z0 * b12;
            ss0 += __sinf(p0); cs0 += __cosf(p0);
            ss1 += __sinf(p1); cs1 += __cosf(p1);
        }
    }
    if (s0 < s1) {
        float* gp = g_gpool + g * CAT_DIM + GNN_DIM;
        atomicAdd(&gp[si0 * 256 + c0], ss0);
        atomicAdd(&gp[si0 * 256 + 128 + c0], cs0);
        atomicAdd(&gp[si1 * 256 + c0], ss1);
        atomicAdd(&gp[si1 * 256 + 128 + c0], cs1);
    }
}

// ---------------------------------------------------------------------------
// Final: out = LN(gpool/cnt @ Wfc + bfc)   (64 blocks x 256 threads)
// ---------------------------------------------------------------------------
__global__ __launch_bounds__(256) void final_kernel(
        const float* __restrict__ Wfc, const float* __restrict__ bfc,
        const float* __restrict__ gfc, const float* __restrict__ befc,
        float* __restrict__ out) {
    int g = blockIdx.x, t = threadIdx.x;
    int beg = g_goff[g], end = g_goff[g + 1];
    float inv = 1.f / (float)max(end - beg, 1);
    __shared__ float hg[CAT_DIM];
    for (int i = t; i < CAT_DIM; i += 256) hg[i] = g_gpool[g * CAT_DIM + i] * inv;
    __syncthreads();
    float acc = bfc[t];
    for (int k = 0; k < CAT_DIM; ++k) acc = fmaf(hg[k], Wfc[(size_t)k * OUT_DIM + t], acc);
    float sum = acc, sq = acc * acc;
    #pragma unroll
    for (int off = 32; off; off >>= 1) { sum += __shfl_xor(sum, off); sq += __shfl_xor(sq, off); }
    __shared__ float s1[4], s2[4];
    if ((t & 63) == 0) { s1[t >> 6] = sum; s2[t >> 6] = sq; }
    __syncthreads();
    sum = s1[0] + s1[1] + s1[2] + s1[3];
    sq  = s2[0] + s2[1] + s2[2] + s2[3];
    float mu = sum * (1.f / OUT_DIM);
    float var = sq * (1.f / OUT_DIM) - mu * mu;
    float rstd = rsqrtf(var + 1e-5f);
    out[g * OUT_DIM + t] = (acc - mu) * rstd * gfc[t] + befc[t];
}

// ---------------------------------------------------------------------------
extern "C" void kernel_launch(void* const* d_in, const int* in_sizes, int n_in,
                              void* d_out, int out_size, void* d_ws, size_t ws_size,
                              hipStream_t stream) {
    const float* x      = (const float*)d_in[0];
    const int*   ei     = (const int*)d_in[1];
    const float* coords = (const float*)d_in[2];
    const int*   batch  = (const int*)d_in[3];
    const float* Bmat   = (const float*)d_in[4];
    const float* W1l    = (const float*)d_in[5];
    const float* b1     = (const float*)d_in[6];
    const float* W1r    = (const float*)d_in[7];
    const float* g1     = (const float*)d_in[8];
    const float* be1    = (const float*)d_in[9];
    const float* W2l    = (const float*)d_in[10];
    const float* b2     = (const float*)d_in[11];
    const float* W2r    = (const float*)d_in[12];
    const float* g2     = (const float*)d_in[13];
    const float* be2    = (const float*)d_in[14];
    const float* Wfc    = (const float*)d_in[15];
    const float* bfc    = (const float*)d_in[16];
    const float* gfc    = (const float*)d_in[17];
    const float* befc   = (const float*)d_in[18];
    const int* src = ei;
    const int* dst = ei + N_EDGES;
    float* out = (float*)d_out;
    (void)in_sizes; (void)n_in; (void)out_size; (void)d_ws; (void)ws_size;

    unsigned short* w2lt;  hipGetSymbolAddress((void**)&w2lt, HIP_SYMBOL(g_w2lt));
    unsigned short* w2rt;  hipGetSymbolAddress((void**)&w2rt, HIP_SYMBOL(g_w2rt));

    zero_kernel<<<512, 256, 0, stream>>>();
    count_kernel<<<(N_EDGES + 255) / 256, 256, 0, stream>>>(dst, batch);
    scan_kernel<<<1, 1024, 0, stream>>>();
    scatter_kernel<<<(N_EDGES + 255) / 256, 256, 0, stream>>>(src, dst);

    transpose_bf16<<<2048, 256, 0, stream>>>(W2l, W2r, w2lt, w2rt);

    l1_agg_kernel<<<(N_NODES * 8 + 255) / 256, 256, 0, stream>>>(x);
    l1_transform_kernel<<<N_NODES / 8, 256, 0, stream>>>(x, W1l, b1, W1r, g1, be1);

    l2_agg_kernel<<<N_NODES / 4, 256, 0, stream>>>();

    gemm2_kernel<<<(M_PAD / BM) * (GNN_DIM / BN), 256, 0, stream>>>(b2);

    pool_h_kernel<<<N_GRAPHS * 8, 256, 0, stream>>>(g2, be2);
    pool_f_kernel<<<N_GRAPHS * 4, 256, 0, stream>>>(coords, Bmat);

    final_kernel<<<N_GRAPHS, 256, 0, stream>>>(Wfc, bfc, gfc, befc, out);
}

// Round 11
// 786.194 us; speedup vs baseline: 1.1811x; 1.0184x over previous
//
#include <hip/hip_runtime.h>
#include <hip/hip_bf16.h>

// ---------------------------------------------------------------------------
// GraphEncoder: SAGE(6->1024) -> LN -> ReLU -> SAGE(1024->1024) -> LN -> ReLU
//   -> concat(Fourier feats) -> per-graph mean pool -> FC(2048->256) -> LN
// R9 config (passing, 801us): bf16 GEMM (888 TF), fp8 gather side-copy.
// R10's fp8-weight GEMM exceeded threshold (0.0625>0.0616) -> reverted.
// Kept from R10: count+transpose fusion, merged pool dispatch.
// ---------------------------------------------------------------------------

#define N_NODES 50000
#define N_EDGES 500000
#define N_GRAPHS 64
#define IN_DIM 6
#define GNN_DIM 1024
#define OUT_DIM 256
#define CAT_DIM 2048
#define M_PAD 50176   // 392 * 128  (392 = 8 XCDs * 49 row-groups)

typedef __attribute__((ext_vector_type(8))) short short8;
typedef __attribute__((ext_vector_type(4))) float f32x4;

#if defined(__has_builtin)
#if __has_builtin(__builtin_amdgcn_cvt_pk_fp8_f32) && __has_builtin(__builtin_amdgcn_cvt_pk_f32_fp8)
#define HW_FP8 1
#endif
#endif

// ---------------- static device scratch (allocated at module load) ---------
__device__ int g_cnt[N_NODES + 1];
__device__ int g_cursor[N_NODES];
__device__ int g_gcnt[N_GRAPHS];
__device__ int g_rowptr[N_NODES + 1];
__device__ int g_goff[N_GRAPHS + 1];
__device__ int g_esrc[N_EDGES];
__device__ __attribute__((aligned(256))) unsigned short g_w2lt[(size_t)GNN_DIM * GNN_DIM];
__device__ __attribute__((aligned(256))) unsigned short g_w2rt[(size_t)GNN_DIM * GNN_DIM];
__device__ float g_agg1[(size_t)N_NODES * IN_DIM];
__device__ __attribute__((aligned(256))) unsigned short g_h[(size_t)M_PAD * GNN_DIM];
__device__ __attribute__((aligned(256))) unsigned g_h8w[(size_t)M_PAD * (GNN_DIM / 4)];
__device__ __attribute__((aligned(256))) unsigned short g_agg2[(size_t)M_PAD * GNN_DIM];
__device__ __attribute__((aligned(256))) unsigned short g_h2[(size_t)M_PAD * GNN_DIM];
__device__ float g_gpool[(size_t)N_GRAPHS * CAT_DIM];

__device__ __forceinline__ float bflo(int u) { return __uint_as_float(((unsigned)u) << 16); }
__device__ __forceinline__ float bfhi(int u) { return __uint_as_float(((unsigned)u) & 0xffff0000u); }
__device__ __forceinline__ unsigned short f2bf(float f) {
    unsigned u = __float_as_uint(f);
    unsigned rounded = u + 0x7fff + ((u >> 16) & 1);   // RNE
    return (unsigned short)(rounded >> 16);
}
__device__ __forceinline__ int pack2(unsigned short a, unsigned short b) {
    return (int)((unsigned)a | ((unsigned)b << 16));
}

#ifndef HW_FP8
// software e4m3 codec (FTZ, RNE, clamp 448); inputs are >=0 (post-ReLU)
__device__ __forceinline__ unsigned enc8(float f) {
    if (!(f >= 0.015625f)) return 0;     // below min normal -> 0
    if (f > 448.f) f = 448.f;
    unsigned u = __float_as_uint(f);
    u += 0x7FFFF + ((u >> 20) & 1);      // RNE at bit 20
    unsigned e = (u >> 23) & 0xFF;
    return ((e - 120) << 3) | ((u >> 20) & 7);
}
__device__ __forceinline__ float dec8(unsigned b) {
    unsigned e = (b >> 3) & 15, m = b & 7;
    unsigned f = ((e + 120) << 23) | (m << 20);
    return e ? __uint_as_float(f) : 0.f;
}
#endif

// ---------------------------------------------------------------------------
// zero + CSR build
// ---------------------------------------------------------------------------
__global__ void zero_kernel() {          // grid 512 -> 131072 threads
    int i = blockIdx.x * 256 + threadIdx.x;
    if (i <= N_NODES) g_cnt[i] = 0;
    if (i < N_NODES) g_cursor[i] = 0;
    if (i < N_GRAPHS) g_gcnt[i] = 0;
    if (i < N_GRAPHS * CAT_DIM) g_gpool[i] = 0.f;
}

// count (blocks 0..1953) + weight transpose->bf16 (blocks 1954..4001)
#define CNT_BLOCKS 1954
__global__ void count_transpose_kernel(const int* __restrict__ dst,
                                       const int* __restrict__ batch,
                                       const float* __restrict__ WA,
                                       const float* __restrict__ WB) {
    __shared__ float tile[32][33];
    if (blockIdx.x < CNT_BLOCKS) {
        int i = blockIdx.x * 256 + threadIdx.x;
        if (i < N_EDGES) atomicAdd(&g_cnt[dst[i]], 1);
        if (i < N_NODES) atomicAdd(&g_gcnt[batch[i]], 1);
        return;
    }
    int bid = blockIdx.x - CNT_BLOCKS;       // 0..2047
    int id = bid & 1023;
    const float* W = (bid >> 10) ? WB : WA;
    unsigned short* Wt = (bid >> 10) ? g_w2rt : g_w2lt;
    int bx = id & 31, by = id >> 5;
    int tx = threadIdx.x & 31, ty = threadIdx.x >> 5;  // 32x8
    for (int i = 0; i < 32; i += 8)
        tile[ty + i][tx] = W[(size_t)(by * 32 + ty + i) * GNN_DIM + bx * 32 + tx];
    __syncthreads();
    for (int i = 0; i < 32; i += 8)
        Wt[(size_t)(bx * 32 + ty + i) * GNN_DIM + by * 32 + tx] = f2bf(tile[tx][ty + i]);
}

// two-level scan (rowptr) + graph-offset prefix (goff) in one kernel
__global__ __launch_bounds__(1024) void scan_kernel() {
    const int CH = 49;           // 1024 * 49 = 50176 >= N_NODES+1
    int t = threadIdx.x;
    int base = t * CH;
    int s = 0;
    #pragma unroll
    for (int i = 0; i < CH; ++i) {
        int n = base + i;
        s += (n < N_NODES) ? g_cnt[n] : 0;
    }
    int lane = t & 63, w = t >> 6;
    int x = s;
    #pragma unroll
    for (int off = 1; off < 64; off <<= 1) {
        int y = __shfl_up(x, off);
        if (lane >= off) x += y;
    }
    __shared__ int wsum[16], woff[16];
    if (lane == 63) wsum[w] = x;
    __syncthreads();
    if (t == 0) { int a = 0; for (int i = 0; i < 16; ++i) { woff[i] = a; a += wsum[i]; } }
    __syncthreads();
    int excl = x - s + woff[w];      // exclusive prefix at chunk start
    #pragma unroll
    for (int i = 0; i < CH; ++i) {
        int n = base + i;
        if (n <= N_NODES) g_rowptr[n] = excl;
        if (n < N_NODES) excl += g_cnt[n];
    }
    // goff: 64-thread wave prefix over g_gcnt
    if (t < 64) {
        int v = g_gcnt[t];
        int xx = v;
        #pragma unroll
        for (int off = 1; off < 64; off <<= 1) {
            int y = __shfl_up(xx, off);
            if ((t & 63) >= off) xx += y;
        }
        g_goff[t + 1] = xx;
        if (t == 0) g_goff[0] = 0;
    }
}

__global__ void scatter_kernel(const int* __restrict__ src, const int* __restrict__ dst) {
    int e = blockIdx.x * 256 + threadIdx.x;
    if (e >= N_EDGES) return;
    int d = dst[e];
    int pos = atomicAdd(&g_cursor[d], 1);
    g_esrc[g_rowptr[d] + pos] = src[e];
}

// ---------------------------------------------------------------------------
// Layer 1: mean-agg of x (6-dim), transform, LN, ReLU -> h (bf16) + h8 (fp8)
// ---------------------------------------------------------------------------
__global__ void l1_agg_kernel(const float* __restrict__ x) {
    int id = blockIdx.x * 256 + threadIdx.x;
    int n = id >> 3, slot = id & 7;
    if (n >= N_NODES || slot >= IN_DIM) return;
    int beg = g_rowptr[n], end = g_rowptr[n + 1];
    float s = 0.f;
    for (int i = beg; i < end; ++i) s += x[(size_t)g_esrc[i] * IN_DIM + slot];
    g_agg1[n * IN_DIM + slot] = s / (float)max(end - beg, 1);
}

// 8 nodes per block; weights held in registers (dims t*4..t*4+3 per thread)
__global__ __launch_bounds__(256) void l1_transform_kernel(
        const float* __restrict__ x,
        const float* __restrict__ W1l, const float* __restrict__ b1,
        const float* __restrict__ W1r, const float* __restrict__ g1,
        const float* __restrict__ be1) {
    int t = threadIdx.x;
    int nb = blockIdx.x * 8;                 // 6250 blocks * 8 = 50000 exact
    float4 wl[6], wr[6];
    #pragma unroll
    for (int k = 0; k < 6; ++k) {
        wl[k] = *(const float4*)&W1l[k * GNN_DIM + t * 4];
        wr[k] = *(const float4*)&W1r[k * GNN_DIM + t * 4];
    }
    float4 bb = *(const float4*)&b1[t * 4];
    float4 gg = *(const float4*)&g1[t * 4];
    float4 be = *(const float4*)&be1[t * 4];
    __shared__ float sx[48], sa[48];
    if (t < 48) sx[t] = x[nb * 6 + t];
    else if (t < 96) sa[t - 48] = g_agg1[nb * 6 + (t - 48)];
    __syncthreads();
    __shared__ float s1[4], s2[4];
    for (int u = 0; u < 8; ++u) {
        int n = nb + u;
        float4 v = bb;
        #pragma unroll
        for (int k = 0; k < 6; ++k) {
            float a = sa[u * 6 + k], xx = sx[u * 6 + k];
            v.x += a * wl[k].x + xx * wr[k].x;
            v.y += a * wl[k].y + xx * wr[k].y;
            v.z += a * wl[k].z + xx * wr[k].z;
            v.w += a * wl[k].w + xx * wr[k].w;
        }
        float sum = v.x + v.y + v.z + v.w;
        float sq  = v.x*v.x + v.y*v.y + v.z*v.z + v.w*v.w;
        #pragma unroll
        for (int off = 32; off; off >>= 1) { sum += __shfl_xor(sum, off); sq += __shfl_xor(sq, off); }
        if ((t & 63) == 0) { s1[t >> 6] = sum; s2[t >> 6] = sq; }
        __syncthreads();
        sum = s1[0] + s1[1] + s1[2] + s1[3];
        sq  = s2[0] + s2[1] + s2[2] + s2[3];
        __syncthreads();
        float mu = sum * (1.f / GNN_DIM);
        float var = sq * (1.f / GNN_DIM) - mu * mu;
        float rstd = rsqrtf(var + 1e-5f);
        float y0 = fmaxf((v.x - mu) * rstd * gg.x + be.x, 0.f);
        float y1 = fmaxf((v.y - mu) * rstd * gg.y + be.y, 0.f);
        float y2 = fmaxf((v.z - mu) * rstd * gg.z + be.z, 0.f);
        float y3 = fmaxf((v.w - mu) * rstd * gg.w + be.w, 0.f);
        int2 pk;
        pk.x = pack2(f2bf(y0), f2bf(y1));
        pk.y = pack2(f2bf(y2), f2bf(y3));
        *(int2*)(g_h + (size_t)n * GNN_DIM + t * 4) = pk;
#ifdef HW_FP8
        int p8 = __builtin_amdgcn_cvt_pk_fp8_f32(y0, y1, 0, false);
        p8 = __builtin_amdgcn_cvt_pk_fp8_f32(y2, y3, p8, true);
        g_h8w[(size_t)n * 256 + t] = (unsigned)p8;
#else
        g_h8w[(size_t)n * 256 + t] =
            enc8(y0) | (enc8(y1) << 8) | (enc8(y2) << 16) | (enc8(y3) << 24);
#endif
    }
}

// ---------------------------------------------------------------------------
// Layer 2 aggregation: agg2[n] = mean of h8[src] rows (fp8 gather, half the
// bytes of bf16). Wave-per-node; 1 int4/lane = full 1KB row; 8-edge batches.
// ---------------------------------------------------------------------------
#ifdef HW_FP8
#define DEC_ACC(word, b) do { \
    auto p0_ = __builtin_amdgcn_cvt_pk_f32_fp8((int)(word), false); \
    auto p1_ = __builtin_amdgcn_cvt_pk_f32_fp8((int)(word), true);  \
    s[(b)+0] += m * p0_[0]; s[(b)+1] += m * p0_[1]; \
    s[(b)+2] += m * p1_[0]; s[(b)+3] += m * p1_[1]; } while (0)
#else
#define DEC_ACC(word, b) do { unsigned w_ = (unsigned)(word); \
    s[(b)+0] += m * dec8(w_ & 255);        s[(b)+1] += m * dec8((w_ >> 8) & 255); \
    s[(b)+2] += m * dec8((w_ >> 16) & 255); s[(b)+3] += m * dec8(w_ >> 24); } while (0)
#endif

__global__ __launch_bounds__(256) void l2_agg_kernel() {
    int w = threadIdx.x >> 6, lane = threadIdx.x & 63;
    int n = blockIdx.x * 4 + w;              // 12500 blocks * 4 = 50000 exact
    int beg = g_rowptr[n], end = g_rowptr[n + 1];
    float s[16];
    #pragma unroll
    for (int j = 0; j < 16; ++j) s[j] = 0.f;
    const int4* hp = (const int4*)g_h8w;     // row = 64 int4 (1 KB)
    for (int i = beg; i < end; i += 8) {
        int idx[8]; float msk[8]; int4 v[8];
        #pragma unroll
        for (int j = 0; j < 8; ++j) {
            int e = i + j;
            int cl = (e < end) ? e : beg;    // beg valid since loop entered
            idx[j] = g_esrc[cl];
            msk[j] = (e < end) ? 1.f : 0.f;
        }
        #pragma unroll
        for (int j = 0; j < 8; ++j) v[j] = hp[(size_t)idx[j] * 64 + lane];
        #pragma unroll
        for (int j = 0; j < 8; ++j) {
            float m = msk[j];
            DEC_ACC(v[j].x, 0); DEC_ACC(v[j].y, 4);
            DEC_ACC(v[j].z, 8); DEC_ACC(v[j].w, 12);
        }
    }
    float inv = 1.f / (float)max(end - beg, 1);
    int4 o0, o1;
    o0.x = pack2(f2bf(s[0] * inv),  f2bf(s[1] * inv));
    o0.y = pack2(f2bf(s[2] * inv),  f2bf(s[3] * inv));
    o0.z = pack2(f2bf(s[4] * inv),  f2bf(s[5] * inv));
    o0.w = pack2(f2bf(s[6] * inv),  f2bf(s[7] * inv));
    o1.x = pack2(f2bf(s[8] * inv),  f2bf(s[9] * inv));
    o1.y = pack2(f2bf(s[10] * inv), f2bf(s[11] * inv));
    o1.z = pack2(f2bf(s[12] * inv), f2bf(s[13] * inv));
    o1.w = pack2(f2bf(s[14] * inv), f2bf(s[15] * inv));
    // lane owns dims 16*lane .. 16*lane+15
    *(int4*)(g_agg2 + (size_t)n * GNN_DIM + (size_t)lane * 16) = o0;
    *(int4*)(g_agg2 + (size_t)n * GNN_DIM + (size_t)lane * 16 + 8) = o1;
}

// ---------------------------------------------------------------------------
// Layer 2 GEMM: h2 = agg2 @ W2_l + h @ W2_r + b2  (bf16 MFMA)
// XCD-bijective tile remap + XOR swizzle; clean bias+store epilogue.
// (R6-measured: 237 us, 888 TF, 0 bank conflicts)
// ---------------------------------------------------------------------------
#define BM 128
#define BN 128
#define BK 64

__global__ __launch_bounds__(256) void gemm2_kernel(const float* __restrict__ bias) {
    __shared__ __attribute__((aligned(16))) unsigned short As[BM * BK];
    __shared__ __attribute__((aligned(16))) unsigned short Bs[BN * BK];
    int i = blockIdx.x;
    int xcd = i & 7;
    int j = i >> 3;                 // 0..391
    int bm = xcd * 49 + (j >> 3);   // 0..391
    int bn = j & 7;
    int row0 = bm * BM, col0 = bn * BN;
    int t = threadIdx.x;
    int lane = t & 63, wid = t >> 6;
    int wr = wid >> 1, wc = wid & 1;     // 2x2 waves, each owns 64x64
    f32x4 acc[4][4] = {};
    int c0 = t;
    for (int seg = 0; seg < 2; ++seg) {
        const unsigned short* A  = seg ? g_h : g_agg2;
        const unsigned short* Bt = seg ? g_w2rt : g_w2lt;
        for (int k0 = 0; k0 < GNN_DIM; k0 += BK) {
            __syncthreads();
            #pragma unroll
            for (int u = 0; u < 4; ++u) {
                int c = c0 + u * 256;
                int r = c >> 3;
                int kb = (c & 7) * 16;                  // byte offset within row
                int kbs = kb ^ ((r & 7) << 4);          // inverse-swizzled source
                __builtin_amdgcn_global_load_lds(
                    (const __attribute__((address_space(1))) void*)(A + (size_t)(row0 + r) * GNN_DIM + k0 + (kbs >> 1)),
                    (__attribute__((address_space(3))) void*)(As + c * 8), 16, 0, 0);
            }
            #pragma unroll
            for (int u = 0; u < 4; ++u) {
                int c = c0 + u * 256;
                int r = c >> 3;
                int kb = (c & 7) * 16;
                int kbs = kb ^ ((r & 7) << 4);
                __builtin_amdgcn_global_load_lds(
                    (const __attribute__((address_space(1))) void*)(Bt + (size_t)(col0 + r) * GNN_DIM + k0 + (kbs >> 1)),
                    (__attribute__((address_space(3))) void*)(Bs + c * 8), 16, 0, 0);
            }
            asm volatile("s_waitcnt vmcnt(0)" ::: "memory");
            __syncthreads();
            #pragma unroll
            for (int kk = 0; kk < BK; kk += 32) {
                short8 a[4], b[4];
                int krd = kk + (lane >> 4) * 8;          // short index in row
                #pragma unroll
                for (int m = 0; m < 4; ++m) {
                    int row = wr * 64 + m * 16 + (lane & 15);
                    int ks = ((krd * 2) ^ ((row & 7) << 4)) >> 1;   // swizzled read
                    a[m] = *(const short8*)&As[row * BK + ks];
                }
                #pragma unroll
                for (int n = 0; n < 4; ++n) {
                    int row = wc * 64 + n * 16 + (lane & 15);
                    int ks = ((krd * 2) ^ ((row & 7) << 4)) >> 1;
                    b[n] = *(const short8*)&Bs[row * BK + ks];
                }
                #pragma unroll
                for (int m = 0; m < 4; ++m)
                    #pragma unroll
                    for (int n = 0; n < 4; ++n)
                        acc[m][n] = __builtin_amdgcn_mfma_f32_16x16x32_bf16(a[m], b[n], acc[m][n], 0, 0, 0);
            }
        }
    }
    #pragma unroll
    for (int m = 0; m < 4; ++m) {
        #pragma unroll
        for (int n = 0; n < 4; ++n) {
            int col = col0 + wc * 64 + n * 16 + (lane & 15);
            int rbase = row0 + wr * 64 + m * 16 + (lane >> 4) * 4;
            float bv = bias[col];
            #pragma unroll
            for (int r = 0; r < 4; ++r) {
                float v = acc[m][n][r] + bv;
                g_h2[(size_t)(rbase + r) * GNN_DIM + col] = f2bf(v);
            }
        }
    }
}

// ---------------------------------------------------------------------------
// Pool merged: blocks 0..511 = h-part (wave-per-node LN+ReLU+mean);
// blocks 512..767 = fourier part.
// ---------------------------------------------------------------------------
__global__ __launch_bounds__(256) void pool_kernel(
        const float* __restrict__ g2, const float* __restrict__ be2,
        const float* __restrict__ coords, const float* __restrict__ Bmat) {
    __shared__ float lacc[4][GNN_DIM];   // 16 KB (h path)
    __shared__ float sc[256 * 3];        //  3 KB (fourier path)
    int t = threadIdx.x;
    if (blockIdx.x < 512) {
        int g = blockIdx.x >> 3, sl = blockIdx.x & 7;
        int w = t >> 6, lane = t & 63;
        int beg = g_goff[g], end = g_goff[g + 1];
        int cnt = end - beg;
        int per = (cnt + 7) >> 3;
        int s0 = beg + sl * per, s1v = min(s0 + per, end);
        if (s0 >= s1v) return;               // block-uniform
        float gA[8], bA[8], gB[8], bB[8];
        #pragma unroll
        for (int j = 0; j < 8; ++j) {
            gA[j] = g2[8 * lane + j];        bA[j] = be2[8 * lane + j];
            gB[j] = g2[512 + 8 * lane + j];  bB[j] = be2[512 + 8 * lane + j];
        }
        float aA[8], aB[8];
        #pragma unroll
        for (int j = 0; j < 8; ++j) { aA[j] = 0.f; aB[j] = 0.f; }
        for (int n = s0 + w; n < s1v; n += 4) {
            const int4* rp = (const int4*)(g_h2 + (size_t)n * GNN_DIM);
            int4 w0 = rp[lane], w1 = rp[64 + lane];
            float vA[8] = { bflo(w0.x), bfhi(w0.x), bflo(w0.y), bfhi(w0.y),
                            bflo(w0.z), bfhi(w0.z), bflo(w0.w), bfhi(w0.w) };
            float vB[8] = { bflo(w1.x), bfhi(w1.x), bflo(w1.y), bfhi(w1.y),
                            bflo(w1.z), bfhi(w1.z), bflo(w1.w), bfhi(w1.w) };
            float sum = 0.f, sq = 0.f;
            #pragma unroll
            for (int j = 0; j < 8; ++j) {
                sum += vA[j] + vB[j];
                sq  += vA[j] * vA[j] + vB[j] * vB[j];
            }
            #pragma unroll
            for (int off = 32; off; off >>= 1) { sum += __shfl_xor(sum, off); sq += __shfl_xor(sq, off); }
            float mu = sum * (1.f / GNN_DIM);
            float var = sq * (1.f / GNN_DIM) - mu * mu;
            float rstd = rsqrtf(var + 1e-5f);
            #pragma unroll
            for (int j = 0; j < 8; ++j) {
                aA[j] += fmaxf((vA[j] - mu) * rstd * gA[j] + bA[j], 0.f);
                aB[j] += fmaxf((vB[j] - mu) * rstd * gB[j] + bB[j], 0.f);
            }
        }
        #pragma unroll
        for (int j = 0; j < 8; ++j) {
            lacc[w][8 * lane + j] = aA[j];
            lacc[w][512 + 8 * lane + j] = aB[j];
        }
        __syncthreads();
        #pragma unroll
        for (int q = 0; q < 4; ++q) {
            int d = t * 4 + q;
            float r = lacc[0][d] + lacc[1][d] + lacc[2][d] + lacc[3][d];
            atomicAdd(&g_gpool[g * CAT_DIM + d], r);
        }
        return;
    }
    // ---- fourier part ----
    int bid = blockIdx.x - 512;              // 0..255
    int g = bid >> 2, sl = bid & 3;
    int beg = g_goff[g], end = g_goff[g + 1];
    int cnt = end - beg;
    int per = (cnt + 3) >> 2;
    int s0 = beg + sl * per, s1 = min(s0 + per, end);
    const float SC[4] = {1.f, 5.f, 10.f, 30.f};
    int si0 = t >> 7, c0 = t & 127;
    int si1 = si0 + 2;
    float b00 = Bmat[c0] * SC[si0], b01 = Bmat[128 + c0] * SC[si0], b02 = Bmat[256 + c0] * SC[si0];
    float b10 = Bmat[c0] * SC[si1], b11 = Bmat[128 + c0] * SC[si1], b12 = Bmat[256 + c0] * SC[si1];
    float ss0 = 0.f, cs0 = 0.f, ss1 = 0.f, cs1 = 0.f;
    for (int base = s0; base < s1; base += 256) {
        int m = min(256, s1 - base);
        __syncthreads();
        for (int q = t; q < 3 * m; q += 256) sc[q] = coords[base * 3 + q];
        __syncthreads();
        for (int i = 0; i < m; ++i) {
            float x0 = sc[i * 3], y0 = sc[i * 3 + 1], z0 = sc[i * 3 + 2];
            float p0 = x0 * b00 + y0 * b01 + z0 * b02;
            float p1 = x0 * b10 + y0 * b11 + z0 * b12;
            ss0 += __sinf(p0); cs0 += __cosf(p0);
            ss1 += __sinf(p1); cs1 += __cosf(p1);
        }
    }
    if (s0 < s1) {
        float* gp = g_gpool + g * CAT_DIM + GNN_DIM;
        atomicAdd(&gp[si0 * 256 + c0], ss0);
        atomicAdd(&gp[si0 * 256 + 128 + c0], cs0);
        atomicAdd(&gp[si1 * 256 + c0], ss1);
        atomicAdd(&gp[si1 * 256 + 128 + c0], cs1);
    }
}

// ---------------------------------------------------------------------------
// Final: out = LN(gpool/cnt @ Wfc + bfc)   (64 blocks x 256 threads)
// ---------------------------------------------------------------------------
__global__ __launch_bounds__(256) void final_kernel(
        const float* __restrict__ Wfc, const float* __restrict__ bfc,
        const float* __restrict__ gfc, const float* __restrict__ befc,
        float* __restrict__ out) {
    int g = blockIdx.x, t = threadIdx.x;
    int beg = g_goff[g], end = g_goff[g + 1];
    float inv = 1.f / (float)max(end - beg, 1);
    __shared__ float hg[CAT_DIM];
    for (int i = t; i < CAT_DIM; i += 256) hg[i] = g_gpool[g * CAT_DIM + i] * inv;
    __syncthreads();
    float acc = bfc[t];
    for (int k = 0; k < CAT_DIM; ++k) acc = fmaf(hg[k], Wfc[(size_t)k * OUT_DIM + t], acc);
    float sum = acc, sq = acc * acc;
    #pragma unroll
    for (int off = 32; off; off >>= 1) { sum += __shfl_xor(sum, off); sq += __shfl_xor(sq, off); }
    __shared__ float s1[4], s2[4];
    if ((t & 63) == 0) { s1[t >> 6] = sum; s2[t >> 6] = sq; }
    __syncthreads();
    sum = s1[0] + s1[1] + s1[2] + s1[3];
    sq  = s2[0] + s2[1] + s2[2] + s2[3];
    float mu = sum * (1.f / OUT_DIM);
    float var = sq * (1.f / OUT_DIM) - mu * mu;
    float rstd = rsqrtf(var + 1e-5f);
    out[g * OUT_DIM + t] = (acc - mu) * rstd * gfc[t] + befc[t];
}

// ---------------------------------------------------------------------------
extern "C" void kernel_launch(void* const* d_in, const int* in_sizes, int n_in,
                              void* d_out, int out_size, void* d_ws, size_t ws_size,
                              hipStream_t stream) {
    const float* x      = (const float*)d_in[0];
    const int*   ei     = (const int*)d_in[1];
    const float* coords = (const float*)d_in[2];
    const int*   batch  = (const int*)d_in[3];
    const float* Bmat   = (const float*)d_in[4];
    const float* W1l    = (const float*)d_in[5];
    const float* b1     = (const float*)d_in[6];
    const float* W1r    = (const float*)d_in[7];
    const float* g1     = (const float*)d_in[8];
    const float* be1    = (const float*)d_in[9];
    const float* W2l    = (const float*)d_in[10];
    const float* b2     = (const float*)d_in[11];
    const float* W2r    = (const float*)d_in[12];
    const float* g2     = (const float*)d_in[13];
    const float* be2    = (const float*)d_in[14];
    const float* Wfc    = (const float*)d_in[15];
    const float* bfc    = (const float*)d_in[16];
    const float* gfc    = (const float*)d_in[17];
    const float* befc   = (const float*)d_in[18];
    const int* src = ei;
    const int* dst = ei + N_EDGES;
    float* out = (float*)d_out;
    (void)in_sizes; (void)n_in; (void)out_size; (void)d_ws; (void)ws_size;

    zero_kernel<<<512, 256, 0, stream>>>();
    count_transpose_kernel<<<CNT_BLOCKS + 2048, 256, 0, stream>>>(dst, batch, W2l, W2r);
    scan_kernel<<<1, 1024, 0, stream>>>();
    scatter_kernel<<<(N_EDGES + 255) / 256, 256, 0, stream>>>(src, dst);

    l1_agg_kernel<<<(N_NODES * 8 + 255) / 256, 256, 0, stream>>>(x);
    l1_transform_kernel<<<N_NODES / 8, 256, 0, stream>>>(x, W1l, b1, W1r, g1, be1);

    l2_agg_kernel<<<N_NODES / 4, 256, 0, stream>>>();

    gemm2_kernel<<<(M_PAD / BM) * (GNN_DIM / BN), 256, 0, stream>>>(b2);

    pool_kernel<<<512 + 256, 256, 0, stream>>>(g2, be2, coords, Bmat);

    final_kernel<<<N_GRAPHS, 256, 0, stream>>>(Wfc, bfc, gfc, befc, out);
}